// Round 4
// baseline (3748.417 us; speedup 1.0000x reference)
//
#include <hip/hip_runtime.h>
#include <cstdint>
#include <cstddef>

#define B_    4
#define N_TOK 1029
#define C_    1024
#define H_    16
#define DH_   64
#define L_    8
#define HID_  4096
#define M_TOK (B_*N_TOK)   // 4116
#define MP2_  4352         // 17 * 256
#define GMT_  17           // M tiles of 256
#define KVT_  17           // ceil(1029/64)

typedef float f32x4 __attribute__((ext_vector_type(4)));
typedef short bf16x8 __attribute__((ext_vector_type(8)));

__device__ __forceinline__ uint16_t f2bf(float f) {
  uint32_t u = __float_as_uint(f);
  u += 0x7fffu + ((u >> 16) & 1u);   // round-to-nearest-even
  return (uint16_t)(u >> 16);
}

__device__ __forceinline__ void async_copy16(const uint16_t* src, uint16_t* lds_dst) {
  __builtin_amdgcn_global_load_lds(
      (const __attribute__((address_space(1))) void*)src,
      (__attribute__((address_space(3))) void*)lds_dst, 16, 0, 0);
}

// byte offset into a [rows][64] bf16 LDS tile with XOR swizzle (slot ^= row&7)
__device__ __forceinline__ int swz16(int row, int byte_in_row) {
  return row * 128 + (byte_in_row ^ ((row & 7) << 4));
}

// ---------------- weight conversion fp32 -> bf16 ----------------
__global__ __launch_bounds__(256)
void cvt_f32_bf16(const float* __restrict__ in, uint16_t* __restrict__ out, int n4) {
  int i = blockIdx.x * 256 + threadIdx.x;
  if (i < n4) {
    float4 v = reinterpret_cast<const float4*>(in)[i];
    uint64_t pk = (uint64_t)f2bf(v.x) | ((uint64_t)f2bf(v.y) << 16)
                | ((uint64_t)f2bf(v.z) << 32) | ((uint64_t)f2bf(v.w) << 48);
    reinterpret_cast<uint64_t*>(out)[i] = pk;
  }
}

// ---------------- LayerNorm (fp32 in, bf16 or fp32 out) ----------------
template<int OUTMODE>  // 0: bf16 out, 1: fp32 out
__global__ __launch_bounds__(256)
void ln_fwd(const float* __restrict__ x, const float* __restrict__ w,
            const float* __restrict__ b, void* __restrict__ outp) {
  const int row = blockIdx.x;
  const int tid = threadIdx.x;
  const float4 v = reinterpret_cast<const float4*>(x + (size_t)row * C_)[tid];
  float s  = v.x + v.y + v.z + v.w;
  float s2 = v.x*v.x + v.y*v.y + v.z*v.z + v.w*v.w;
  #pragma unroll
  for (int d = 1; d < 64; d <<= 1) {
    s  += __shfl_xor(s, d);
    s2 += __shfl_xor(s2, d);
  }
  __shared__ float red[8];
  const int wv = tid >> 6;
  if ((tid & 63) == 0) { red[wv] = s; red[wv + 4] = s2; }
  __syncthreads();
  s  = red[0] + red[1] + red[2] + red[3];
  s2 = red[4] + red[5] + red[6] + red[7];
  const float mu = s * (1.0f / C_);
  const float rs = rsqrtf(fmaxf(s2 * (1.0f / C_) - mu * mu, 0.0f) + 1e-6f);
  const float4 wv4 = reinterpret_cast<const float4*>(w)[tid];
  const float4 bv4 = reinterpret_cast<const float4*>(b)[tid];
  const float o0 = (v.x - mu) * rs * wv4.x + bv4.x;
  const float o1 = (v.y - mu) * rs * wv4.y + bv4.y;
  const float o2 = (v.z - mu) * rs * wv4.z + bv4.z;
  const float o3 = (v.w - mu) * rs * wv4.w + bv4.w;
  if (OUTMODE == 0) {
    uint64_t pk = (uint64_t)f2bf(o0) | ((uint64_t)f2bf(o1) << 16)
                | ((uint64_t)f2bf(o2) << 32) | ((uint64_t)f2bf(o3) << 48);
    reinterpret_cast<uint64_t*>((uint16_t*)outp + (size_t)row * C_)[tid] = pk;
  } else {
    float4 o; o.x = o0; o.y = o1; o.z = o2; o.w = o3;
    reinterpret_cast<float4*>((float*)outp + (size_t)row * C_)[tid] = o;
  }
}

// ---------------- GEMM: 256x128 tile, BK=64, 4 waves (2x2, wave-tile 128x64) ----
// Single-buffered LDS (48 KB) -> 2 independent blocks/CU for TLP overlap.
// Optional split-K (KCH chunks of KC): EPI 3 stores fp32 partials to pbuf.
// EPI 0: store bf16. EPI 1: GELU(exact) -> bf16. EPI 3: partial fp32 (no bias).
template<int EPI>
__global__ __launch_bounds__(256, 4)
void gemm4(const uint16_t* __restrict__ A, const uint16_t* __restrict__ W,
           const float* __restrict__ bias, uint16_t* __restrict__ outb,
           float* __restrict__ pbuf, int Nn, int Ktot, int KC) {
  __shared__ uint16_t As[4][64 * 64];   // 32 KB: 4 bands of 64 rows
  __shared__ uint16_t Bs[2][64 * 64];   // 16 KB: 2 bands of 64 rows

  // bijective XCD swizzle (m204), then bm-major decode (kc slowest)
  const int nwg = (int)gridDim.x;
  const int q8 = nwg >> 3, r8 = nwg & 7;
  const int xcd = (int)blockIdx.x & 7, pos = (int)blockIdx.x >> 3;
  const int wgid = (xcd < r8 ? xcd * (q8 + 1) : r8 * (q8 + 1) + (xcd - r8) * q8) + pos;
  const int NB = Nn >> 7;
  const int kc  = wgid / (GMT_ * NB);
  const int rem = wgid % (GMT_ * NB);
  const int bm = rem / NB, bn = rem % NB;

  const int tid = (int)threadIdx.x;
  const int l = tid & 63, w = tid >> 6;
  const int l15 = l & 15, l4 = l >> 4;
  const int wr = w >> 1, wc = w & 1;          // 2 x 2 waves
  const int srow = tid >> 3;                  // 0..31 (staging sub-row)
  const int sslot = tid & 7;

  const uint16_t* Ag = A + (size_t)bm * 256 * Ktot + (size_t)kc * KC;
  const uint16_t* Wg = W + (size_t)bn * 128 * Ktot + (size_t)kc * KC;

  f32x4 acc[8][4] = {};

  const int nt = KC >> 6;
  for (int t = 0; t < nt; ++t) {
    __syncthreads();   // previous tile's reads done before overwrite
    const int k0 = t * 64;
    // stage A: 4 bands x (2 issues of 32 rows); source-swizzled, linear LDS
    #pragma unroll
    for (int bnd = 0; bnd < 4; ++bnd) {
      #pragma unroll
      for (int jj = 0; jj < 2; ++jj) {
        const int row = jj * 32 + srow;                  // 0..63 in band
        const int slot = sslot ^ (row & 7);
        async_copy16(Ag + (size_t)(bnd * 64 + row) * Ktot + k0 + slot * 8,
                     &As[bnd][0] + jj * 2048 + tid * 8);
      }
    }
    // stage B: 2 bands x 2 issues
    #pragma unroll
    for (int bnd = 0; bnd < 2; ++bnd) {
      #pragma unroll
      for (int jj = 0; jj < 2; ++jj) {
        const int row = jj * 32 + srow;
        const int slot = sslot ^ (row & 7);
        async_copy16(Wg + (size_t)(bnd * 64 + row) * Ktot + k0 + slot * 8,
                     &Bs[bnd][0] + jj * 2048 + tid * 8);
      }
    }
    __syncthreads();   // drain staging

    #pragma unroll
    for (int kk = 0; kk < 2; ++kk) {
      bf16x8 af[8], bfr[4];
      #pragma unroll
      for (int i = 0; i < 8; ++i) {
        const int R = wr * 128 + i * 16 + l15;
        const int bnd = R >> 6, r = R & 63;
        af[i] = *(const bf16x8*)((const char*)&As[bnd][0] + swz16(r, kk * 64 + l4 * 16));
      }
      #pragma unroll
      for (int j = 0; j < 4; ++j) {
        const int r = wc * 64 + j * 16 + l15 - wc * 64;  // = j*16+l15
        bfr[j] = *(const bf16x8*)((const char*)&Bs[wc][0] + swz16(j * 16 + l15, kk * 64 + l4 * 16));
      }
      #pragma unroll
      for (int i = 0; i < 8; ++i)
        #pragma unroll
        for (int j = 0; j < 4; ++j)
          acc[i][j] = __builtin_amdgcn_mfma_f32_16x16x32_bf16(af[i], bfr[j], acc[i][j], 0, 0, 0);
    }
  }

  // epilogue
  #pragma unroll
  for (int j = 0; j < 4; ++j) {
    const int col = bn * 128 + wc * 64 + j * 16 + l15;
    const float bv = (EPI == 3) ? 0.0f : bias[col];
    #pragma unroll
    for (int i = 0; i < 8; ++i) {
      const int mbase = bm * 256 + wr * 128 + i * 16 + l4 * 4;
      #pragma unroll
      for (int r = 0; r < 4; ++r) {
        const int m = mbase + r;
        const float v = acc[i][j][r] + bv;
        if (EPI == 0) {
          outb[(size_t)m * Nn + col] = f2bf(v);
        } else if (EPI == 1) {
          const float g = 0.5f * v * (1.0f + erff(v * 0.70710678118f));
          outb[(size_t)m * Nn + col] = f2bf(g);
        } else {
          pbuf[((size_t)kc * MP2_ + m) * Nn + col] = v;
        }
      }
    }
  }
}

// ---------------- split-K reduce: xbuf[m,:] += bias + sum_kc pbuf[kc,m,:] ----------------
template<int KCH>
__global__ __launch_bounds__(256)
void reduce_add(const float* __restrict__ pbuf, const float* __restrict__ bias,
                float* __restrict__ xbuf) {
  const int m = blockIdx.x;          // < M_TOK
  const int c4 = threadIdx.x;        // 256 * float4 = 1024 cols
  float4 s = reinterpret_cast<const float4*>(bias)[c4];
  #pragma unroll
  for (int kc = 0; kc < KCH; ++kc) {
    const float4 pv = reinterpret_cast<const float4*>(pbuf + ((size_t)kc * MP2_ + m) * C_)[c4];
    s.x += pv.x; s.y += pv.y; s.z += pv.z; s.w += pv.w;
  }
  float4 x = reinterpret_cast<float4*>(xbuf + (size_t)m * C_)[c4];
  x.x += s.x; x.y += s.y; x.z += s.z; x.w += s.w;
  reinterpret_cast<float4*>(xbuf + (size_t)m * C_)[c4] = x;
}

// ---------------- Flash attention: qkv [.,3072] bf16 -> o [.,1024] bf16 ----------------
__global__ __launch_bounds__(256, 2)
void attn_fwd(const uint16_t* __restrict__ qkv, uint16_t* __restrict__ ob) {
  __shared__ uint16_t Ksm_[64 * 64];       // [key][d], source-swizzled
  __shared__ uint16_t Vsm_[64 * 64];       // transposed: [d][key], XOR-swizzled
  __shared__ uint16_t Psm_[4][16 * 72];    // per wave: [16 q][64 key + pad]

  const int tid = threadIdx.x;
  const int l = tid & 63, w = tid >> 6;
  const int l15 = l & 15, l4 = l >> 4;
  const int bh = blockIdx.x;
  const int b = bh >> 4, h = bh & 15;
  const int qt = blockIdx.y;
  const int rsub = l >> 3;
  const int ssl = (l & 7) ^ rsub;

  bf16x8 qf[2];
  {
    const int qrow = qt * 64 + w * 16 + l15;
    const uint16_t* qbase = qkv + (size_t)(b * N_TOK + qrow) * 3072 + h * 64;
    qf[0] = *(const bf16x8*)(qbase + l4 * 8);
    qf[1] = *(const bf16x8*)(qbase + 32 + l4 * 8);
  }

  float mrow[4], lrow[4];
  f32x4 oacc[4] = {};
  #pragma unroll
  for (int r = 0; r < 4; ++r) { mrow[r] = -1e30f; lrow[r] = 0.0f; }

  for (int kt = 0; kt < KVT_; ++kt) {
    const int key0 = kt * 64;
    __syncthreads();
    #pragma unroll
    for (int cc = 0; cc < 2; ++cc) {
      const int c = w * 2 + cc;
      const int krow = c * 8 + rsub;
      const uint16_t* src = qkv + (size_t)(b * N_TOK + key0 + krow) * 3072 + 1024 + h * 64 + ssl * 8;
      async_copy16(src, Ksm_ + c * 512);
    }
    {
      const int a  = tid & 7;
      const int kb = tid >> 3;
      #pragma unroll
      for (int it = 0; it < 2; ++it) {
        const int key = kb + it * 32;
        const bf16x8 vv = *(const bf16x8*)(qkv + (size_t)(b * N_TOK + key0 + key) * 3072 + 2048 + h * 64 + a * 8);
        #pragma unroll
        for (int j = 0; j < 8; ++j) {
          const int d = a * 8 + j;
          const int byteoff = d * 128 + ((key * 2) ^ ((((d & 7) ^ ((d >> 3) & 7))) << 4));
          *(uint16_t*)((char*)Vsm_ + byteoff) = (uint16_t)vv[j];
        }
      }
    }
    __syncthreads();

    f32x4 s[4] = {};
    #pragma unroll
    for (int kk = 0; kk < 2; ++kk) {
      #pragma unroll
      for (int kf = 0; kf < 4; ++kf) {
        const int r = kf * 16 + l15;
        const bf16x8 kfrag = *(const bf16x8*)((const char*)Ksm_ + swz16(r, kk * 64 + l4 * 16));
        s[kf] = __builtin_amdgcn_mfma_f32_16x16x32_bf16(qf[kk], kfrag, s[kf], 0, 0, 0);
      }
    }
    float mnew[4] = {-1e30f, -1e30f, -1e30f, -1e30f};
    #pragma unroll
    for (int kf = 0; kf < 4; ++kf) {
      const bool valid = (key0 + kf * 16 + l15) < N_TOK;
      #pragma unroll
      for (int r = 0; r < 4; ++r) {
        const float sv = valid ? s[kf][r] * 0.125f : -1e30f;
        s[kf][r] = sv;
        mnew[r] = fmaxf(mnew[r], sv);
      }
    }
    #pragma unroll
    for (int r = 0; r < 4; ++r) {
      #pragma unroll
      for (int dlt = 1; dlt < 16; dlt <<= 1)
        mnew[r] = fmaxf(mnew[r], __shfl_xor(mnew[r], dlt));
    }
    #pragma unroll
    for (int r = 0; r < 4; ++r) {
      const float mi = fmaxf(mrow[r], mnew[r]);
      const float sc = __expf(mrow[r] - mi);
      mrow[r] = mi;
      lrow[r] *= sc;
      #pragma unroll
      for (int d = 0; d < 4; ++d) oacc[d][r] *= sc;
    }
    float psum[4] = {0.f, 0.f, 0.f, 0.f};
    #pragma unroll
    for (int kf = 0; kf < 4; ++kf) {
      #pragma unroll
      for (int r = 0; r < 4; ++r) {
        const float p = __expf(s[kf][r] - mrow[r]);
        psum[r] += p;
        Psm_[w][(l4 * 4 + r) * 72 + kf * 16 + l15] = f2bf(p);
      }
    }
    #pragma unroll
    for (int r = 0; r < 4; ++r) {
      #pragma unroll
      for (int dlt = 1; dlt < 16; dlt <<= 1)
        psum[r] += __shfl_xor(psum[r], dlt);
      lrow[r] += psum[r];
    }
    #pragma unroll
    for (int kk = 0; kk < 2; ++kk) {
      const bf16x8 pf = *(const bf16x8*)(&Psm_[w][l15 * 72 + kk * 32 + l4 * 8]);
      #pragma unroll
      for (int df = 0; df < 4; ++df) {
        const int d = df * 16 + l15;
        const int byteoff = d * 128 + ((kk * 64 + l4 * 16) ^ ((((d & 7) ^ ((d >> 3) & 7))) << 4));
        const bf16x8 vf = *(const bf16x8*)((const char*)Vsm_ + byteoff);
        oacc[df] = __builtin_amdgcn_mfma_f32_16x16x32_bf16(pf, vf, oacc[df], 0, 0, 0);
      }
    }
  }
  #pragma unroll
  for (int r = 0; r < 4; ++r) {
    const int q = qt * 64 + w * 16 + l4 * 4 + r;
    if (q < N_TOK) {
      const float inv = 1.0f / lrow[r];
      #pragma unroll
      for (int df = 0; df < 4; ++df)
        ob[(size_t)(b * N_TOK + q) * 1024 + h * 64 + df * 16 + l15] = f2bf(oacc[df][r] * inv);
    }
  }
}

extern "C" void kernel_launch(void* const* d_in, const int* in_sizes, int n_in,
                              void* d_out, int out_size, void* d_ws, size_t ws_size,
                              hipStream_t stream) {
  const float* x_in   = (const float*)d_in[0];
  const float* ln1_w  = (const float*)d_in[1];
  const float* ln1_b  = (const float*)d_in[2];
  const float* qkv_w  = (const float*)d_in[3];
  const float* qkv_b  = (const float*)d_in[4];
  const float* proj_w = (const float*)d_in[5];
  const float* proj_b = (const float*)d_in[6];
  const float* ln2_w  = (const float*)d_in[7];
  const float* ln2_b  = (const float*)d_in[8];
  const float* fc1_w  = (const float*)d_in[9];
  const float* fc1_b  = (const float*)d_in[10];
  const float* fc2_w  = (const float*)d_in[11];
  const float* fc2_b  = (const float*)d_in[12];
  const float* norm_w = (const float*)d_in[13];
  const float* norm_b = (const float*)d_in[14];

  char* p = (char*)d_ws;
  float*    xbuf = (float*)p;     p += (size_t)MP2_ * C_ * 4;
  uint16_t* hbuf = (uint16_t*)p;  p += (size_t)MP2_ * C_ * 2;   // LN out / attn out
  uint16_t* big  = (uint16_t*)p;  p += (size_t)MP2_ * HID_ * 2; // qkv / hid
  uint16_t* wq   = (uint16_t*)p;  p += (size_t)L_ * 3 * C_ * C_ * 2;
  uint16_t* wp   = (uint16_t*)p;  p += (size_t)L_ * C_ * C_ * 2;
  uint16_t* w1   = (uint16_t*)p;  p += (size_t)L_ * HID_ * C_ * 2;
  uint16_t* w2   = (uint16_t*)p;  p += (size_t)L_ * C_ * HID_ * 2;
  float*    pbuf = (float*)p;     p += (size_t)4 * MP2_ * C_ * 4;   // split-K partials
  if ((size_t)(p - (char*)d_ws) > ws_size) return;  // fail loudly (output stays poisoned)

  hipMemcpyAsync(xbuf, x_in, (size_t)M_TOK * C_ * sizeof(float),
                 hipMemcpyDeviceToDevice, stream);

  auto cvt = [&](const float* src, uint16_t* dst, size_t n) {
    const int n4 = (int)(n / 4);
    cvt_f32_bf16<<<dim3((n4 + 255) / 256), dim3(256), 0, stream>>>(src, dst, n4);
  };
  cvt(qkv_w,  wq, (size_t)L_ * 3 * C_ * C_);
  cvt(proj_w, wp, (size_t)L_ * C_ * C_);
  cvt(fc1_w,  w1, (size_t)L_ * HID_ * C_);
  cvt(fc2_w,  w2, (size_t)L_ * C_ * HID_);

  for (int lyr = 0; lyr < L_; ++lyr) {
    ln_fwd<0><<<dim3(M_TOK), dim3(256), 0, stream>>>(
        xbuf, ln1_w + (size_t)lyr * C_, ln1_b + (size_t)lyr * C_, hbuf);
    // qkv: [M,3072] = hbuf @ wq^T, no split
    gemm4<0><<<dim3(GMT_ * (3 * C_ / 128)), dim3(256), 0, stream>>>(
        hbuf, wq + (size_t)lyr * 3 * C_ * C_, qkv_b + (size_t)lyr * 3 * C_,
        big, nullptr, 3 * C_, C_, C_);
    attn_fwd<<<dim3(B_ * H_, KVT_), dim3(256), 0, stream>>>(big, hbuf);
    // proj: split-K 2 x 512 -> partials -> reduce (+bias +residual)
    gemm4<3><<<dim3(2 * GMT_ * (C_ / 128)), dim3(256), 0, stream>>>(
        hbuf, wp + (size_t)lyr * C_ * C_, nullptr,
        nullptr, pbuf, C_, C_, C_ / 2);
    reduce_add<2><<<dim3(M_TOK), dim3(256), 0, stream>>>(
        pbuf, proj_b + (size_t)lyr * C_, xbuf);
    ln_fwd<0><<<dim3(M_TOK), dim3(256), 0, stream>>>(
        xbuf, ln2_w + (size_t)lyr * C_, ln2_b + (size_t)lyr * C_, hbuf);
    // fc1: [M,4096], GELU fused, no split
    gemm4<1><<<dim3(GMT_ * (HID_ / 128)), dim3(256), 0, stream>>>(
        hbuf, w1 + (size_t)lyr * HID_ * C_, fc1_b + (size_t)lyr * HID_,
        big, nullptr, HID_, C_, C_);
    // fc2: split-K 4 x 1024 -> partials -> reduce (+bias +residual)
    gemm4<3><<<dim3(4 * GMT_ * (C_ / 128)), dim3(256), 0, stream>>>(
        big, w2 + (size_t)lyr * C_ * HID_, nullptr,
        nullptr, pbuf, C_, HID_, HID_ / 4);
    reduce_add<4><<<dim3(M_TOK), dim3(256), 0, stream>>>(
        pbuf, fc2_b + (size_t)lyr * C_, xbuf);
  }
  ln_fwd<1><<<dim3(M_TOK), dim3(256), 0, stream>>>(xbuf, norm_w, norm_b, d_out);
}

// Round 5
// 3077.773 us; speedup vs baseline: 1.2179x; 1.2179x over previous
//
#include <hip/hip_runtime.h>
#include <cstdint>
#include <cstddef>

#define B_    4
#define N_TOK 1029
#define C_    1024
#define H_    16
#define DH_   64
#define L_    8
#define HID_  4096
#define M_TOK (B_*N_TOK)   // 4116
#define MP2_  4352         // 34 * 128
#define GMB_  34           // m tiles of 128
#define KVT_  17           // ceil(1029/64)

typedef float f32x4 __attribute__((ext_vector_type(4)));
typedef short bf16x8 __attribute__((ext_vector_type(8)));

__device__ __forceinline__ uint16_t f2bf(float f) {
  uint32_t u = __float_as_uint(f);
  u += 0x7fffu + ((u >> 16) & 1u);   // round-to-nearest-even
  return (uint16_t)(u >> 16);
}

__device__ __forceinline__ void async_copy16(const uint16_t* src, uint16_t* lds_dst) {
  __builtin_amdgcn_global_load_lds(
      (const __attribute__((address_space(1))) void*)src,
      (__attribute__((address_space(3))) void*)lds_dst, 16, 0, 0);
}

// byte offset into a [rows][64] bf16 LDS tile with XOR swizzle (slot ^= row&7)
__device__ __forceinline__ int swz16(int row, int byte_in_row) {
  return row * 128 + (byte_in_row ^ ((row & 7) << 4));
}

// ===== packed fragment layout =====
// element (m,k) of a [rows][K] matrix lives at:
//   (((pm*steps + kk)*4 + i)*64 + lane)*8 + e
// pm=m>>6, i=(m>>4)&3, kk=k>>5, lane=((k>>3)&3)*16 + (m&15), e=k&7, steps=K>>5.
// A wave's MFMA fragment (pm,kk,i) = 64 lanes x 16B contiguous (1 KB).

// ---------------- weight pack fp32 -> bf16 fragments (dest-coalesced) ----------------
__global__ __launch_bounds__(256)
void cvt_packB(const float* __restrict__ in, uint16_t* __restrict__ out,
               int K, int logsteps, int matsize) {
  const int lyr = blockIdx.y;
  const int t = blockIdx.x * 256 + threadIdx.x;   // octet id within matrix
  const int lane = t & 63;
  const int j = (t >> 6) & 3;
  const int kk = (t >> 8) & ((1 << logsteps) - 1);
  const int pn = t >> (8 + logsteps);
  const int n = pn * 64 + j * 16 + (lane & 15);
  const int k0 = (kk << 5) + (lane >> 4) * 8;
  const float* src = in + (size_t)lyr * matsize + (size_t)n * K + k0;
  const float4 v0 = *(const float4*)(src);
  const float4 v1 = *(const float4*)(src + 4);
  uint64_t p0 = (uint64_t)f2bf(v0.x) | ((uint64_t)f2bf(v0.y) << 16)
              | ((uint64_t)f2bf(v0.z) << 32) | ((uint64_t)f2bf(v0.w) << 48);
  uint64_t p1 = (uint64_t)f2bf(v1.x) | ((uint64_t)f2bf(v1.y) << 16)
              | ((uint64_t)f2bf(v1.z) << 32) | ((uint64_t)f2bf(v1.w) << 48);
  uint64_t* dst = (uint64_t*)(out + (size_t)lyr * matsize + (size_t)t * 8);
  dst[0] = p0; dst[1] = p1;
}

// ---------------- LayerNorm ----------------
// OUTMODE 1: fp32 row-major out. OUTMODE 2: bf16 packed-A out (K=1024, steps=32).
template<int OUTMODE>
__global__ __launch_bounds__(256)
void ln_fwd(const float* __restrict__ x, const float* __restrict__ w,
            const float* __restrict__ b, void* __restrict__ outp) {
  const int row = blockIdx.x;
  const int tid = threadIdx.x;
  const float4 v = reinterpret_cast<const float4*>(x + (size_t)row * C_)[tid];
  float s  = v.x + v.y + v.z + v.w;
  float s2 = v.x*v.x + v.y*v.y + v.z*v.z + v.w*v.w;
  #pragma unroll
  for (int d = 1; d < 64; d <<= 1) {
    s  += __shfl_xor(s, d);
    s2 += __shfl_xor(s2, d);
  }
  __shared__ float red[8];
  const int wv = tid >> 6;
  if ((tid & 63) == 0) { red[wv] = s; red[wv + 4] = s2; }
  __syncthreads();
  s  = red[0] + red[1] + red[2] + red[3];
  s2 = red[4] + red[5] + red[6] + red[7];
  const float mu = s * (1.0f / C_);
  const float rs = rsqrtf(fmaxf(s2 * (1.0f / C_) - mu * mu, 0.0f) + 1e-6f);
  const float4 wv4 = reinterpret_cast<const float4*>(w)[tid];
  const float4 bv4 = reinterpret_cast<const float4*>(b)[tid];
  const float o0 = (v.x - mu) * rs * wv4.x + bv4.x;
  const float o1 = (v.y - mu) * rs * wv4.y + bv4.y;
  const float o2 = (v.z - mu) * rs * wv4.z + bv4.z;
  const float o3 = (v.w - mu) * rs * wv4.w + bv4.w;
  if (OUTMODE == 2) {
    const int c0 = tid * 4;
    const int kk = c0 >> 5, l4p = (c0 >> 3) & 3, e0 = c0 & 7;   // e0 in {0,4}
    const int pm = row >> 6, ii = (row >> 4) & 3;
    const int lanep = l4p * 16 + (row & 15);
    const uint64_t pk = (uint64_t)f2bf(o0) | ((uint64_t)f2bf(o1) << 16)
                      | ((uint64_t)f2bf(o2) << 32) | ((uint64_t)f2bf(o3) << 48);
    uint16_t* op = (uint16_t*)outp;
    *(uint64_t*)(op + ((((size_t)pm * 32 + kk) * 4 + ii) * 64 + lanep) * 8 + e0) = pk;
  } else {
    float4 o; o.x = o0; o.y = o1; o.z = o2; o.w = o3;
    reinterpret_cast<float4*>((float*)outp + (size_t)row * C_)[tid] = o;
  }
}

// ---------------- register GEMM: C[m,n] = sum_k A[m,k]*W[n,k] + bias[n] ----------------
// No LDS, no barriers. A and B both in packed-fragment layout. 128x128 block tile,
// 4 waves (2x2), wave-tile 64x64 (acc 4x4). Each frag load = 1 coalesced 1 KB read.
// EPI 0: row-major bf16. EPI 1: GELU -> packed bf16 (outKsteps = Nn>>5). EPI 2: fp32 resid +=.
template<int EPI>
__global__ __launch_bounds__(256)
void gemm_reg(const uint16_t* __restrict__ Apk, const uint16_t* __restrict__ Bpk,
              const float* __restrict__ bias, uint16_t* __restrict__ outb,
              float* __restrict__ resid, int Nn, int K, int outKsteps) {
  // bijective XCD chunking; bn-major (consecutive wgid share bn -> B panel L2-resident)
  const int nwg = (int)gridDim.x;
  const int q8 = nwg >> 3, r8 = nwg & 7;
  const int xcd = (int)blockIdx.x & 7, pos = (int)blockIdx.x >> 3;
  const int wgid = (xcd < r8 ? xcd * (q8 + 1) : r8 * (q8 + 1) + (xcd - r8) * q8) + pos;
  const int bn = wgid / GMB_, bm = wgid % GMB_;

  const int tid = (int)threadIdx.x;
  const int l = tid & 63, w = tid >> 6;
  const int l15 = l & 15, l4 = l >> 4;
  const int wr = w >> 1, wc = w & 1;
  const int steps = K >> 5;

  const uint16_t* Aw = Apk + ((size_t)(bm * 2 + wr) * steps) * 2048 + l * 8;
  const uint16_t* Bw = Bpk + ((size_t)(bn * 2 + wc) * steps) * 2048 + l * 8;

  f32x4 acc[4][4] = {};
  bf16x8 a0[4], b0[4], a1[4], b1[4];

  auto ld0 = [&](int s) {
    const uint16_t* ap = Aw + (size_t)s * 2048;
    const uint16_t* bp = Bw + (size_t)s * 2048;
    #pragma unroll
    for (int i = 0; i < 4; ++i) a0[i] = *(const bf16x8*)(ap + i * 512);
    #pragma unroll
    for (int j = 0; j < 4; ++j) b0[j] = *(const bf16x8*)(bp + j * 512);
  };
  auto ld1 = [&](int s) {
    const uint16_t* ap = Aw + (size_t)s * 2048;
    const uint16_t* bp = Bw + (size_t)s * 2048;
    #pragma unroll
    for (int i = 0; i < 4; ++i) a1[i] = *(const bf16x8*)(ap + i * 512);
    #pragma unroll
    for (int j = 0; j < 4; ++j) b1[j] = *(const bf16x8*)(bp + j * 512);
  };
  auto mm0 = [&] {
    #pragma unroll
    for (int i = 0; i < 4; ++i)
      #pragma unroll
      for (int j = 0; j < 4; ++j)
        acc[i][j] = __builtin_amdgcn_mfma_f32_16x16x32_bf16(a0[i], b0[j], acc[i][j], 0, 0, 0);
  };
  auto mm1 = [&] {
    #pragma unroll
    for (int i = 0; i < 4; ++i)
      #pragma unroll
      for (int j = 0; j < 4; ++j)
        acc[i][j] = __builtin_amdgcn_mfma_f32_16x16x32_bf16(a1[i], b1[j], acc[i][j], 0, 0, 0);
  };

  ld0(0);
  for (int s = 0; s + 2 <= steps; s += 2) {   // steps is even (32 or 128)
    ld1(s + 1);
    mm0();
    if (s + 2 < steps) ld0(s + 2);
    mm1();
  }

  // epilogue
  #pragma unroll
  for (int j = 0; j < 4; ++j) {
    const int col = bn * 128 + wc * 64 + j * 16 + l15;
    const float bv = (EPI == 1 || EPI == 0 || EPI == 2) ? bias[col] : 0.0f;
    #pragma unroll
    for (int i = 0; i < 4; ++i) {
      const int mb = bm * 128 + wr * 64 + i * 16 + l4 * 4;
      #pragma unroll
      for (int r = 0; r < 4; ++r) {
        const int m = mb + r;
        const float v = acc[i][j][r] + bv;
        if (EPI == 0) {
          outb[(size_t)m * Nn + col] = f2bf(v);
        } else if (EPI == 1) {
          const float g = 0.5f * v * (1.0f + erff(v * 0.70710678118f));
          const int pm = m >> 6, ii = (m >> 4) & 3;
          const int kk = col >> 5, l4p = (col >> 3) & 3, e = col & 7;
          const int lanep = l4p * 16 + (m & 15);
          outb[((((size_t)pm * outKsteps + kk) * 4 + ii) * 64 + lanep) * 8 + e] = f2bf(g);
        } else {
          if (m < M_TOK) resid[(size_t)m * Nn + col] += v;
        }
      }
    }
  }
}

// ---------------- Flash attention: qkv row-major bf16 -> o packed-A bf16 (K=1024) ----------------
__global__ __launch_bounds__(256, 2)
void attn_fwd(const uint16_t* __restrict__ qkv, uint16_t* __restrict__ ob) {
  __shared__ uint16_t Ksm_[64 * 64];       // [key][d], source-swizzled
  __shared__ uint16_t Vsm_[64 * 64];       // transposed: [d][key], XOR-swizzled
  __shared__ uint16_t Psm_[4][16 * 72];    // per wave: [16 q][64 key + pad]

  const int tid = threadIdx.x;
  const int l = tid & 63, w = tid >> 6;
  const int l15 = l & 15, l4 = l >> 4;
  const int bh = blockIdx.x;
  const int b = bh >> 4, h = bh & 15;
  const int qt = blockIdx.y;
  const int rsub = l >> 3;
  const int ssl = (l & 7) ^ rsub;

  bf16x8 qf[2];
  {
    const int qrow = qt * 64 + w * 16 + l15;
    const uint16_t* qbase = qkv + (size_t)(b * N_TOK + qrow) * 3072 + h * 64;
    qf[0] = *(const bf16x8*)(qbase + l4 * 8);
    qf[1] = *(const bf16x8*)(qbase + 32 + l4 * 8);
  }

  float mrow[4], lrow[4];
  f32x4 oacc[4] = {};
  #pragma unroll
  for (int r = 0; r < 4; ++r) { mrow[r] = -1e30f; lrow[r] = 0.0f; }

  for (int kt = 0; kt < KVT_; ++kt) {
    const int key0 = kt * 64;
    __syncthreads();
    #pragma unroll
    for (int cc = 0; cc < 2; ++cc) {
      const int c = w * 2 + cc;
      const int krow = c * 8 + rsub;
      const uint16_t* src = qkv + (size_t)(b * N_TOK + key0 + krow) * 3072 + 1024 + h * 64 + ssl * 8;
      async_copy16(src, Ksm_ + c * 512);
    }
    {
      const int a  = tid & 7;
      const int kb = tid >> 3;
      #pragma unroll
      for (int it = 0; it < 2; ++it) {
        const int key = kb + it * 32;
        const bf16x8 vv = *(const bf16x8*)(qkv + (size_t)(b * N_TOK + key0 + key) * 3072 + 2048 + h * 64 + a * 8);
        #pragma unroll
        for (int j = 0; j < 8; ++j) {
          const int d = a * 8 + j;
          const int byteoff = d * 128 + ((key * 2) ^ ((((d & 7) ^ ((d >> 3) & 7))) << 4));
          *(uint16_t*)((char*)Vsm_ + byteoff) = (uint16_t)vv[j];
        }
      }
    }
    __syncthreads();

    f32x4 s[4] = {};
    #pragma unroll
    for (int kk = 0; kk < 2; ++kk) {
      #pragma unroll
      for (int kf = 0; kf < 4; ++kf) {
        const int r = kf * 16 + l15;
        const bf16x8 kfrag = *(const bf16x8*)((const char*)Ksm_ + swz16(r, kk * 64 + l4 * 16));
        s[kf] = __builtin_amdgcn_mfma_f32_16x16x32_bf16(qf[kk], kfrag, s[kf], 0, 0, 0);
      }
    }
    float mnew[4] = {-1e30f, -1e30f, -1e30f, -1e30f};
    #pragma unroll
    for (int kf = 0; kf < 4; ++kf) {
      const bool valid = (key0 + kf * 16 + l15) < N_TOK;
      #pragma unroll
      for (int r = 0; r < 4; ++r) {
        const float sv = valid ? s[kf][r] * 0.125f : -1e30f;
        s[kf][r] = sv;
        mnew[r] = fmaxf(mnew[r], sv);
      }
    }
    #pragma unroll
    for (int r = 0; r < 4; ++r) {
      #pragma unroll
      for (int dlt = 1; dlt < 16; dlt <<= 1)
        mnew[r] = fmaxf(mnew[r], __shfl_xor(mnew[r], dlt));
    }
    #pragma unroll
    for (int r = 0; r < 4; ++r) {
      const float mi = fmaxf(mrow[r], mnew[r]);
      const float sc = __expf(mrow[r] - mi);
      mrow[r] = mi;
      lrow[r] *= sc;
      #pragma unroll
      for (int d = 0; d < 4; ++d) oacc[d][r] *= sc;
    }
    float psum[4] = {0.f, 0.f, 0.f, 0.f};
    #pragma unroll
    for (int kf = 0; kf < 4; ++kf) {
      #pragma unroll
      for (int r = 0; r < 4; ++r) {
        const float p = __expf(s[kf][r] - mrow[r]);
        psum[r] += p;
        Psm_[w][(l4 * 4 + r) * 72 + kf * 16 + l15] = f2bf(p);
      }
    }
    #pragma unroll
    for (int r = 0; r < 4; ++r) {
      #pragma unroll
      for (int dlt = 1; dlt < 16; dlt <<= 1)
        psum[r] += __shfl_xor(psum[r], dlt);
      lrow[r] += psum[r];
    }
    #pragma unroll
    for (int kk = 0; kk < 2; ++kk) {
      const bf16x8 pf = *(const bf16x8*)(&Psm_[w][l15 * 72 + kk * 32 + l4 * 8]);
      #pragma unroll
      for (int df = 0; df < 4; ++df) {
        const int d = df * 16 + l15;
        const int byteoff = d * 128 + ((kk * 64 + l4 * 16) ^ ((((d & 7) ^ ((d >> 3) & 7))) << 4));
        const bf16x8 vf = *(const bf16x8*)((const char*)Vsm_ + byteoff);
        oacc[df] = __builtin_amdgcn_mfma_f32_16x16x32_bf16(pf, vf, oacc[df], 0, 0, 0);
      }
    }
  }
  // store to packed-A layout (K=1024, steps=32) for proj
  #pragma unroll
  for (int r = 0; r < 4; ++r) {
    const int q = qt * 64 + w * 16 + l4 * 4 + r;
    if (q < N_TOK) {
      const int m = b * N_TOK + q;
      const float inv = 1.0f / lrow[r];
      const int pm = m >> 6, ii = (m >> 4) & 3;
      #pragma unroll
      for (int df = 0; df < 4; ++df) {
        const int c = h * 64 + df * 16 + l15;
        const int kk = c >> 5, l4p = (c >> 3) & 3, e = l15 & 7;
        const int lanep = l4p * 16 + (m & 15);
        ob[((((size_t)pm * 32 + kk) * 4 + ii) * 64 + lanep) * 8 + e] = f2bf(oacc[df][r] * inv);
      }
    }
  }
}

extern "C" void kernel_launch(void* const* d_in, const int* in_sizes, int n_in,
                              void* d_out, int out_size, void* d_ws, size_t ws_size,
                              hipStream_t stream) {
  const float* x_in   = (const float*)d_in[0];
  const float* ln1_w  = (const float*)d_in[1];
  const float* ln1_b  = (const float*)d_in[2];
  const float* qkv_w  = (const float*)d_in[3];
  const float* qkv_b  = (const float*)d_in[4];
  const float* proj_w = (const float*)d_in[5];
  const float* proj_b = (const float*)d_in[6];
  const float* ln2_w  = (const float*)d_in[7];
  const float* ln2_b  = (const float*)d_in[8];
  const float* fc1_w  = (const float*)d_in[9];
  const float* fc1_b  = (const float*)d_in[10];
  const float* fc2_w  = (const float*)d_in[11];
  const float* fc2_b  = (const float*)d_in[12];
  const float* norm_w = (const float*)d_in[13];
  const float* norm_b = (const float*)d_in[14];

  char* p = (char*)d_ws;
  float*    xbuf = (float*)p;     p += (size_t)MP2_ * C_ * 4;
  uint16_t* hbuf = (uint16_t*)p;  p += (size_t)MP2_ * C_ * 2;   // packed A: LN out / attn out
  uint16_t* big  = (uint16_t*)p;  p += (size_t)MP2_ * HID_ * 2; // qkv row-major / fc1 packed
  uint16_t* wq   = (uint16_t*)p;  p += (size_t)L_ * 3 * C_ * C_ * 2;
  uint16_t* wp   = (uint16_t*)p;  p += (size_t)L_ * C_ * C_ * 2;
  uint16_t* w1   = (uint16_t*)p;  p += (size_t)L_ * HID_ * C_ * 2;
  uint16_t* w2   = (uint16_t*)p;  p += (size_t)L_ * C_ * HID_ * 2;
  if ((size_t)(p - (char*)d_ws) > ws_size) return;  // fail loudly (output stays poisoned)

  hipMemcpyAsync(xbuf, x_in, (size_t)M_TOK * C_ * sizeof(float),
                 hipMemcpyDeviceToDevice, stream);

  // pack weights into fragment order (once per call)
  // qkv_w: [3C][C] K=1024 logsteps=5 ; proj_w: [C][C] 5 ; fc1_w: [HID][C] 5 ; fc2_w: [C][HID] 7
  cvt_packB<<<dim3(3 * C_ * C_ / 2048, L_), dim3(256), 0, stream>>>(qkv_w,  wq, C_,   5, 3 * C_ * C_);
  cvt_packB<<<dim3(C_ * C_ / 2048, L_),     dim3(256), 0, stream>>>(proj_w, wp, C_,   5, C_ * C_);
  cvt_packB<<<dim3(HID_ * C_ / 2048, L_),   dim3(256), 0, stream>>>(fc1_w,  w1, C_,   5, HID_ * C_);
  cvt_packB<<<dim3(C_ * HID_ / 2048, L_),   dim3(256), 0, stream>>>(fc2_w,  w2, HID_, 7, C_ * HID_);

  for (int lyr = 0; lyr < L_; ++lyr) {
    ln_fwd<2><<<dim3(M_TOK), dim3(256), 0, stream>>>(
        xbuf, ln1_w + (size_t)lyr * C_, ln1_b + (size_t)lyr * C_, hbuf);
    // qkv: out row-major [m][3072] for attention
    gemm_reg<0><<<dim3((3 * C_ / 128) * GMB_), dim3(256), 0, stream>>>(
        hbuf, wq + (size_t)lyr * 3 * C_ * C_, qkv_b + (size_t)lyr * 3 * C_,
        big, nullptr, 3 * C_, C_, 0);
    attn_fwd<<<dim3(B_ * H_, KVT_), dim3(256), 0, stream>>>(big, hbuf);
    // proj: resid += (bias fused)
    gemm_reg<2><<<dim3((C_ / 128) * GMB_), dim3(256), 0, stream>>>(
        hbuf, wp + (size_t)lyr * C_ * C_, proj_b + (size_t)lyr * C_,
        nullptr, xbuf, C_, C_, 0);
    ln_fwd<2><<<dim3(M_TOK), dim3(256), 0, stream>>>(
        xbuf, ln2_w + (size_t)lyr * C_, ln2_b + (size_t)lyr * C_, hbuf);
    // fc1: GELU -> packed A for fc2 (outKsteps = 4096/32 = 128)
    gemm_reg<1><<<dim3((HID_ / 128) * GMB_), dim3(256), 0, stream>>>(
        hbuf, w1 + (size_t)lyr * HID_ * C_, fc1_b + (size_t)lyr * HID_,
        big, nullptr, HID_, C_, HID_ >> 5);
    // fc2: resid += (bias fused)
    gemm_reg<2><<<dim3((C_ / 128) * GMB_), dim3(256), 0, stream>>>(
        big, w2 + (size_t)lyr * C_ * HID_, fc2_b + (size_t)lyr * C_,
        nullptr, xbuf, C_, HID_, 0);
  }
  ln_fwd<1><<<dim3(M_TOK), dim3(256), 0, stream>>>(xbuf, norm_w, norm_b, d_out);
}

// Round 6
// 2917.198 us; speedup vs baseline: 1.2849x; 1.0550x over previous
//
#include <hip/hip_runtime.h>
#include <cstdint>
#include <cstddef>

#define B_    4
#define N_TOK 1029
#define C_    1024
#define H_    16
#define DH_   64
#define L_    8
#define HID_  4096
#define M_TOK (B_*N_TOK)   // 4116
#define MP2_  4352         // 34 * 128
#define GMB_  34           // m tiles of 128
#define KVB_  128
#define KVT2_ 9            // ceil(1029/128)
#define KPAD_ 1152         // 9*128

typedef float f32x4 __attribute__((ext_vector_type(4)));
typedef short bf16x8 __attribute__((ext_vector_type(8)));

__device__ __forceinline__ uint16_t f2bf(float f) {
  uint32_t u = __float_as_uint(f);
  u += 0x7fffu + ((u >> 16) & 1u);   // round-to-nearest-even
  return (uint16_t)(u >> 16);
}

__device__ __forceinline__ void async_copy16(const uint16_t* src, uint16_t* lds_dst) {
  __builtin_amdgcn_global_load_lds(
      (const __attribute__((address_space(1))) void*)src,
      (__attribute__((address_space(3))) void*)lds_dst, 16, 0, 0);
}

// byte offset into a [rows][64] bf16 LDS tile with XOR swizzle (slot ^= row&7)
__device__ __forceinline__ int swz16(int row, int byte_in_row) {
  return row * 128 + (byte_in_row ^ ((row & 7) << 4));
}

// ===== packed fragment layout =====
// element (m,k) of a [rows][K] matrix lives at:
//   (((pm*steps + kk)*4 + i)*64 + lane)*8 + e
// pm=m>>6, i=(m>>4)&3, kk=k>>5, lane=((k>>3)&3)*16 + (m&15), e=k&7, steps=K>>5.

// ---------------- weight pack fp32 -> bf16 fragments (dest-coalesced) ----------------
__global__ __launch_bounds__(256)
void cvt_packB(const float* __restrict__ in, uint16_t* __restrict__ out,
               int K, int logsteps, int matsize) {
  const int lyr = blockIdx.y;
  const int t = blockIdx.x * 256 + threadIdx.x;   // octet id within matrix
  const int lane = t & 63;
  const int j = (t >> 6) & 3;
  const int kk = (t >> 8) & ((1 << logsteps) - 1);
  const int pn = t >> (8 + logsteps);
  const int n = pn * 64 + j * 16 + (lane & 15);
  const int k0 = (kk << 5) + (lane >> 4) * 8;
  const float* src = in + (size_t)lyr * matsize + (size_t)n * K + k0;
  const float4 v0 = *(const float4*)(src);
  const float4 v1 = *(const float4*)(src + 4);
  uint64_t p0 = (uint64_t)f2bf(v0.x) | ((uint64_t)f2bf(v0.y) << 16)
              | ((uint64_t)f2bf(v0.z) << 32) | ((uint64_t)f2bf(v0.w) << 48);
  uint64_t p1 = (uint64_t)f2bf(v1.x) | ((uint64_t)f2bf(v1.y) << 16)
              | ((uint64_t)f2bf(v1.z) << 32) | ((uint64_t)f2bf(v1.w) << 48);
  uint64_t* dst = (uint64_t*)(out + (size_t)lyr * matsize + (size_t)t * 8);
  dst[0] = p0; dst[1] = p1;
}

// ---------------- LayerNorm ----------------
// OUTMODE 1: fp32 row-major out. OUTMODE 2: bf16 packed-A out (K=1024, steps=32).
template<int OUTMODE>
__global__ __launch_bounds__(256)
void ln_fwd(const float* __restrict__ x, const float* __restrict__ w,
            const float* __restrict__ b, void* __restrict__ outp) {
  const int row = blockIdx.x;
  const int tid = threadIdx.x;
  const float4 v = reinterpret_cast<const float4*>(x + (size_t)row * C_)[tid];
  float s  = v.x + v.y + v.z + v.w;
  float s2 = v.x*v.x + v.y*v.y + v.z*v.z + v.w*v.w;
  #pragma unroll
  for (int d = 1; d < 64; d <<= 1) {
    s  += __shfl_xor(s, d);
    s2 += __shfl_xor(s2, d);
  }
  __shared__ float red[8];
  const int wv = tid >> 6;
  if ((tid & 63) == 0) { red[wv] = s; red[wv + 4] = s2; }
  __syncthreads();
  s  = red[0] + red[1] + red[2] + red[3];
  s2 = red[4] + red[5] + red[6] + red[7];
  const float mu = s * (1.0f / C_);
  const float rs = rsqrtf(fmaxf(s2 * (1.0f / C_) - mu * mu, 0.0f) + 1e-6f);
  const float4 wv4 = reinterpret_cast<const float4*>(w)[tid];
  const float4 bv4 = reinterpret_cast<const float4*>(b)[tid];
  const float o0 = (v.x - mu) * rs * wv4.x + bv4.x;
  const float o1 = (v.y - mu) * rs * wv4.y + bv4.y;
  const float o2 = (v.z - mu) * rs * wv4.z + bv4.z;
  const float o3 = (v.w - mu) * rs * wv4.w + bv4.w;
  if (OUTMODE == 2) {
    const int c0 = tid * 4;
    const int kk = c0 >> 5, l4p = (c0 >> 3) & 3, e0 = c0 & 7;   // e0 in {0,4}
    const int pm = row >> 6, ii = (row >> 4) & 3;
    const int lanep = l4p * 16 + (row & 15);
    const uint64_t pk = (uint64_t)f2bf(o0) | ((uint64_t)f2bf(o1) << 16)
                      | ((uint64_t)f2bf(o2) << 32) | ((uint64_t)f2bf(o3) << 48);
    uint16_t* op = (uint16_t*)outp;
    *(uint64_t*)(op + ((((size_t)pm * 32 + kk) * 4 + ii) * 64 + lanep) * 8 + e0) = pk;
  } else {
    float4 o; o.x = o0; o.y = o1; o.z = o2; o.w = o3;
    reinterpret_cast<float4*>((float*)outp + (size_t)row * C_)[tid] = o;
  }
}

// ---------------- register GEMM: C[m,n] = sum_k A[m,k]*W[n,k] + bias[n] ----------------
// No LDS, no barriers. A and B both in packed-fragment layout. 128x128 block tile,
// 4 waves (2x2), wave-tile 64x64 (acc 4x4).
// EPI 1: GELU -> packed bf16 (outKsteps). EPI 2: fp32 resid +=. EPI 4: qkv head-split
//   (Q scaled 0.125 -> Qp[bh][key][64]; K -> Kp[bh][key][64]; V -> VTp[bh][d][KPAD_]).
template<int EPI>
__global__ __launch_bounds__(256)
void gemm_reg(const uint16_t* __restrict__ Apk, const uint16_t* __restrict__ Bpk,
              const float* __restrict__ bias, uint16_t* __restrict__ outb,
              float* __restrict__ resid, int Nn, int K, int outKsteps,
              uint16_t* __restrict__ Qp, uint16_t* __restrict__ Kp,
              uint16_t* __restrict__ VTp) {
  const int nwg = (int)gridDim.x;
  const int q8 = nwg >> 3, r8 = nwg & 7;
  const int xcd = (int)blockIdx.x & 7, pos = (int)blockIdx.x >> 3;
  const int wgid = (xcd < r8 ? xcd * (q8 + 1) : r8 * (q8 + 1) + (xcd - r8) * q8) + pos;
  const int bn = wgid / GMB_, bm = wgid % GMB_;

  const int tid = (int)threadIdx.x;
  const int l = tid & 63, w = tid >> 6;
  const int l15 = l & 15, l4 = l >> 4;
  const int wr = w >> 1, wc = w & 1;
  const int steps = K >> 5;

  const uint16_t* Aw = Apk + ((size_t)(bm * 2 + wr) * steps) * 2048 + l * 8;
  const uint16_t* Bw = Bpk + ((size_t)(bn * 2 + wc) * steps) * 2048 + l * 8;

  f32x4 acc[4][4] = {};
  bf16x8 a0[4], b0[4], a1[4], b1[4];

  auto ld0 = [&](int s) {
    const uint16_t* ap = Aw + (size_t)s * 2048;
    const uint16_t* bp = Bw + (size_t)s * 2048;
    #pragma unroll
    for (int i = 0; i < 4; ++i) a0[i] = *(const bf16x8*)(ap + i * 512);
    #pragma unroll
    for (int j = 0; j < 4; ++j) b0[j] = *(const bf16x8*)(bp + j * 512);
  };
  auto ld1 = [&](int s) {
    const uint16_t* ap = Aw + (size_t)s * 2048;
    const uint16_t* bp = Bw + (size_t)s * 2048;
    #pragma unroll
    for (int i = 0; i < 4; ++i) a1[i] = *(const bf16x8*)(ap + i * 512);
    #pragma unroll
    for (int j = 0; j < 4; ++j) b1[j] = *(const bf16x8*)(bp + j * 512);
  };
  auto mm0 = [&] {
    #pragma unroll
    for (int i = 0; i < 4; ++i)
      #pragma unroll
      for (int j = 0; j < 4; ++j)
        acc[i][j] = __builtin_amdgcn_mfma_f32_16x16x32_bf16(a0[i], b0[j], acc[i][j], 0, 0, 0);
  };
  auto mm1 = [&] {
    #pragma unroll
    for (int i = 0; i < 4; ++i)
      #pragma unroll
      for (int j = 0; j < 4; ++j)
        acc[i][j] = __builtin_amdgcn_mfma_f32_16x16x32_bf16(a1[i], b1[j], acc[i][j], 0, 0, 0);
  };

  ld0(0);
  for (int s = 0; s + 2 <= steps; s += 2) {
    ld1(s + 1);
    mm0();
    if (s + 2 < steps) ld0(s + 2);
    mm1();
  }

  #pragma unroll
  for (int j = 0; j < 4; ++j) {
    const int col = bn * 128 + wc * 64 + j * 16 + l15;
    const float bv = bias[col];
    #pragma unroll
    for (int i = 0; i < 4; ++i) {
      const int mb = bm * 128 + wr * 64 + i * 16 + l4 * 4;
      #pragma unroll
      for (int r = 0; r < 4; ++r) {
        const int m = mb + r;
        const float v = acc[i][j][r] + bv;
        if (EPI == 1) {
          const float g = 0.5f * v * (1.0f + erff(v * 0.70710678118f));
          const int pm = m >> 6, ii = (m >> 4) & 3;
          const int kk = col >> 5, l4p = (col >> 3) & 3, e = col & 7;
          const int lanep = l4p * 16 + (m & 15);
          outb[((((size_t)pm * outKsteps + kk) * 4 + ii) * 64 + lanep) * 8 + e] = f2bf(g);
        } else if (EPI == 2) {
          if (m < M_TOK) resid[(size_t)m * Nn + col] += v;
        } else {  // EPI == 4: qkv split into per-head panels
          if (m < M_TOK) {
            const int which = col >> 10;          // 0=Q, 1=K, 2=V
            const int h = (col >> 6) & 15;
            const int d = col & 63;
            const int b = m / N_TOK;
            const int key = m - b * N_TOK;
            const int bh = b * 16 + h;
            if (which == 0)      Qp[((size_t)bh * KPAD_ + key) * 64 + d] = f2bf(v * 0.125f);
            else if (which == 1) Kp[((size_t)bh * KPAD_ + key) * 64 + d] = f2bf(v);
            else                 VTp[((size_t)bh * 64 + d) * KPAD_ + key] = f2bf(v);
          }
        }
      }
    }
  }
}

// ---------------- Flash attention (swapped operands, q lane-local) ----------------
// Qp/Kp: [bh][KPAD_][64] (Q pre-scaled by 0.125). VTp: [bh][64][KPAD_].
// Output: packed-A bf16 (K=1024, steps=32) into hbuf.
__global__ __launch_bounds__(256, 3)
void attn_fwd(const uint16_t* __restrict__ Qp, const uint16_t* __restrict__ Kp,
              const uint16_t* __restrict__ VTp, uint16_t* __restrict__ ob) {
  __shared__ uint16_t Ksm_[KVB_ * 64];     // [key][d], swizzled slots
  __shared__ uint16_t Vsm_[64 * KVB_];     // [d][key], swizzled slots
  __shared__ uint16_t Psm_[4][16 * 136];   // per wave: [q=16][keys 128 + pad]

  const int tid = (int)threadIdx.x;
  const int l = tid & 63, w = tid >> 6;
  const int l15 = l & 15, l4 = l >> 4;
  const int bh = (int)blockIdx.x;
  const int qt = (int)blockIdx.y;

  const uint16_t* Kb = Kp + (size_t)bh * KPAD_ * 64;
  const uint16_t* Vb = VTp + (size_t)bh * 64 * KPAD_;

  // Q fragments: B-operand, lane l15 = q-row
  bf16x8 qf[2];
  {
    const int qrow = qt * 64 + w * 16 + l15;
    const uint16_t* qbase = Qp + ((size_t)bh * KPAD_ + qrow) * 64;
    qf[0] = *(const bf16x8*)(qbase + l4 * 8);
    qf[1] = *(const bf16x8*)(qbase + 32 + l4 * 8);
  }

  float mrow = -1e30f, lrow = 0.0f;
  f32x4 oacc[4] = {};

  const int krow_s = tid >> 3;                    // 0..31
  const int kslot_s = (tid & 7) ^ (krow_s & 7);
  const int vd_s = tid >> 4;                      // 0..15
  const int vslot_s = (tid & 15) ^ (vd_s & 15);

  for (int kt = 0; kt < KVT2_; ++kt) {
    const int key0 = kt * KVB_;
    __syncthreads();   // prev tile reads done
    #pragma unroll
    for (int it = 0; it < 4; ++it) {
      const int row = it * 32 + krow_s;
      async_copy16(Kb + (size_t)(key0 + row) * 64 + kslot_s * 8,
                   Ksm_ + it * 2048 + tid * 8);
    }
    #pragma unroll
    for (int it = 0; it < 4; ++it) {
      const int d = it * 16 + vd_s;
      async_copy16(Vb + (size_t)d * KPAD_ + key0 + vslot_s * 8,
                   Vsm_ + it * 2048 + tid * 8);
    }
    __syncthreads();   // staged

    // S^T: s[kf][r] = S[key0 + kf*16 + l4*4 + r][q = l15]
    f32x4 s[8];
    #pragma unroll
    for (int kf = 0; kf < 8; ++kf) s[kf] = f32x4{0.f, 0.f, 0.f, 0.f};
    #pragma unroll
    for (int kk = 0; kk < 2; ++kk) {
      #pragma unroll
      for (int kf = 0; kf < 8; ++kf) {
        const bf16x8 kfrag = *(const bf16x8*)((const char*)Ksm_ + swz16(kf * 16 + l15, kk * 64 + l4 * 16));
        s[kf] = __builtin_amdgcn_mfma_f32_16x16x32_bf16(kfrag, qf[kk], s[kf], 0, 0, 0);
      }
    }
    // mask tail keys
    if (kt == KVT2_ - 1) {
      #pragma unroll
      for (int kf = 0; kf < 8; ++kf)
        #pragma unroll
        for (int r = 0; r < 4; ++r)
          if (key0 + kf * 16 + l4 * 4 + r >= N_TOK) s[kf][r] = -1e30f;
    }
    // row max (31 register fmax + 2 shfl)
    float pmx = s[0][0];
    #pragma unroll
    for (int kf = 0; kf < 8; ++kf)
      #pragma unroll
      for (int r = 0; r < 4; ++r) pmx = fmaxf(pmx, s[kf][r]);
    pmx = fmaxf(pmx, __shfl_xor(pmx, 16));
    pmx = fmaxf(pmx, __shfl_xor(pmx, 32));
    // defer-max (T13)
    if (!__all(pmx - mrow <= 8.0f)) {
      const float mi = fmaxf(mrow, pmx);
      const float sc = __expf(mrow - mi);
      mrow = mi;
      lrow *= sc;
      #pragma unroll
      for (int df = 0; df < 4; ++df)
        #pragma unroll
        for (int r = 0; r < 4; ++r) oacc[df][r] *= sc;
    }
    // P = exp(s - m); pack 4 keys -> one b64 LDS write per kf
    float psum = 0.0f;
    #pragma unroll
    for (int kf = 0; kf < 8; ++kf) {
      const float p0 = __expf(s[kf][0] - mrow);
      const float p1 = __expf(s[kf][1] - mrow);
      const float p2 = __expf(s[kf][2] - mrow);
      const float p3 = __expf(s[kf][3] - mrow);
      psum += (p0 + p1) + (p2 + p3);
      const uint64_t pk = (uint64_t)f2bf(p0) | ((uint64_t)f2bf(p1) << 16)
                        | ((uint64_t)f2bf(p2) << 32) | ((uint64_t)f2bf(p3) << 48);
      *(uint64_t*)(&Psm_[w][l15 * 136 + kf * 16 + l4 * 4]) = pk;
    }
    psum += __shfl_xor(psum, 16);
    psum += __shfl_xor(psum, 32);
    lrow += psum;
    // O^T += V^T P : oacc[df][r] = O[d = df*16 + l4*4 + r][q = l15]
    #pragma unroll
    for (int kk = 0; kk < 4; ++kk) {
      const bf16x8 pf = *(const bf16x8*)(&Psm_[w][l15 * 136 + kk * 32 + l4 * 8]);
      #pragma unroll
      for (int df = 0; df < 4; ++df) {
        const int d = df * 16 + l15;
        const bf16x8 vfrag = *(const bf16x8*)(Vsm_ + d * KVB_ + (((kk * 4 + l4) ^ (d & 15)) * 8));
        oacc[df] = __builtin_amdgcn_mfma_f32_16x16x32_bf16(vfrag, pf, oacc[df], 0, 0, 0);
      }
    }
  }

  // store: O[d][q=l15] -> packed-A layout (K=1024, steps=32)
  const int q = qt * 64 + w * 16 + l15;
  if (q < N_TOK) {
    const float inv = 1.0f / lrow;
    const int m = (bh >> 4) * N_TOK + q;
    const int pmq = m >> 6, ii = (m >> 4) & 3, m15 = m & 15;
    const int hbase = (bh & 15) * 64;
    #pragma unroll
    for (int df = 0; df < 4; ++df)
      #pragma unroll
      for (int r = 0; r < 4; ++r) {
        const int c = hbase + df * 16 + l4 * 4 + r;
        const int kkp = c >> 5, l4p = (c >> 3) & 3, e = c & 7;
        ob[((((size_t)pmq * 32 + kkp) * 4 + ii) * 64 + l4p * 16 + m15) * 8 + e] =
            f2bf(oacc[df][r] * inv);
      }
  }
}

extern "C" void kernel_launch(void* const* d_in, const int* in_sizes, int n_in,
                              void* d_out, int out_size, void* d_ws, size_t ws_size,
                              hipStream_t stream) {
  const float* x_in   = (const float*)d_in[0];
  const float* ln1_w  = (const float*)d_in[1];
  const float* ln1_b  = (const float*)d_in[2];
  const float* qkv_w  = (const float*)d_in[3];
  const float* qkv_b  = (const float*)d_in[4];
  const float* proj_w = (const float*)d_in[5];
  const float* proj_b = (const float*)d_in[6];
  const float* ln2_w  = (const float*)d_in[7];
  const float* ln2_b  = (const float*)d_in[8];
  const float* fc1_w  = (const float*)d_in[9];
  const float* fc1_b  = (const float*)d_in[10];
  const float* fc2_w  = (const float*)d_in[11];
  const float* fc2_b  = (const float*)d_in[12];
  const float* norm_w = (const float*)d_in[13];
  const float* norm_b = (const float*)d_in[14];

  char* p = (char*)d_ws;
  float*    xbuf = (float*)p;     p += (size_t)MP2_ * C_ * 4;
  uint16_t* hbuf = (uint16_t*)p;  p += (size_t)MP2_ * C_ * 2;   // packed A: LN out / attn out
  uint16_t* big  = (uint16_t*)p;  p += (size_t)MP2_ * HID_ * 2; // fc1 packed out
  uint16_t* wq   = (uint16_t*)p;  p += (size_t)L_ * 3 * C_ * C_ * 2;
  uint16_t* wp   = (uint16_t*)p;  p += (size_t)L_ * C_ * C_ * 2;
  uint16_t* w1   = (uint16_t*)p;  p += (size_t)L_ * HID_ * C_ * 2;
  uint16_t* w2   = (uint16_t*)p;  p += (size_t)L_ * C_ * HID_ * 2;
  uint16_t* qp   = (uint16_t*)p;  p += (size_t)64 * KPAD_ * 64 * 2;
  uint16_t* kp   = (uint16_t*)p;  p += (size_t)64 * KPAD_ * 64 * 2;
  uint16_t* vtp  = (uint16_t*)p;  p += (size_t)64 * 64 * KPAD_ * 2;
  if ((size_t)(p - (char*)d_ws) > ws_size) return;  // fail loudly (output stays poisoned)

  hipMemcpyAsync(xbuf, x_in, (size_t)M_TOK * C_ * sizeof(float),
                 hipMemcpyDeviceToDevice, stream);

  // pack weights into fragment order (once per call)
  cvt_packB<<<dim3(3 * C_ * C_ / 2048, L_), dim3(256), 0, stream>>>(qkv_w,  wq, C_,   5, 3 * C_ * C_);
  cvt_packB<<<dim3(C_ * C_ / 2048, L_),     dim3(256), 0, stream>>>(proj_w, wp, C_,   5, C_ * C_);
  cvt_packB<<<dim3(HID_ * C_ / 2048, L_),   dim3(256), 0, stream>>>(fc1_w,  w1, C_,   5, HID_ * C_);
  cvt_packB<<<dim3(C_ * HID_ / 2048, L_),   dim3(256), 0, stream>>>(fc2_w,  w2, HID_, 7, C_ * HID_);

  for (int lyr = 0; lyr < L_; ++lyr) {
    ln_fwd<2><<<dim3(M_TOK), dim3(256), 0, stream>>>(
        xbuf, ln1_w + (size_t)lyr * C_, ln1_b + (size_t)lyr * C_, hbuf);
    // qkv -> per-head panels (Q scaled)
    gemm_reg<4><<<dim3((3 * C_ / 128) * GMB_), dim3(256), 0, stream>>>(
        hbuf, wq + (size_t)lyr * 3 * C_ * C_, qkv_b + (size_t)lyr * 3 * C_,
        nullptr, nullptr, 3 * C_, C_, 0, qp, kp, vtp);
    attn_fwd<<<dim3(64, 17), dim3(256), 0, stream>>>(qp, kp, vtp, hbuf);
    // proj: resid += (bias fused)
    gemm_reg<2><<<dim3((C_ / 128) * GMB_), dim3(256), 0, stream>>>(
        hbuf, wp + (size_t)lyr * C_ * C_, proj_b + (size_t)lyr * C_,
        nullptr, xbuf, C_, C_, 0, nullptr, nullptr, nullptr);
    ln_fwd<2><<<dim3(M_TOK), dim3(256), 0, stream>>>(
        xbuf, ln2_w + (size_t)lyr * C_, ln2_b + (size_t)lyr * C_, hbuf);
    // fc1: GELU -> packed A for fc2
    gemm_reg<1><<<dim3((HID_ / 128) * GMB_), dim3(256), 0, stream>>>(
        hbuf, w1 + (size_t)lyr * HID_ * C_, fc1_b + (size_t)lyr * HID_,
        big, nullptr, HID_, C_, HID_ >> 5, nullptr, nullptr, nullptr);
    // fc2: resid += (bias fused)
    gemm_reg<2><<<dim3((C_ / 128) * GMB_), dim3(256), 0, stream>>>(
        big, w2 + (size_t)lyr * C_ * HID_, fc2_b + (size_t)lyr * C_,
        nullptr, xbuf, C_, HID_, 0, nullptr, nullptr, nullptr);
  }
  ln_fwd<1><<<dim3(M_TOK), dim3(256), 0, stream>>>(xbuf, norm_w, norm_b, d_out);
}

// Round 7
// 2795.243 us; speedup vs baseline: 1.3410x; 1.0436x over previous
//
#include <hip/hip_runtime.h>
#include <cstdint>
#include <cstddef>

#define B_    4
#define N_TOK 1029
#define C_    1024
#define H_    16
#define DH_   64
#define L_    8
#define HID_  4096
#define M_TOK (B_*N_TOK)   // 4116
#define MP2_  4352         // 34 * 128
#define GMB_  34           // m tiles of 128
#define KVB_  128
#define KVT2_ 9            // ceil(1029/128)
#define KPAD_ 1152         // 9*128

typedef float f32x4 __attribute__((ext_vector_type(4)));
typedef short bf16x8 __attribute__((ext_vector_type(8)));

__device__ __forceinline__ uint16_t f2bf(float f) {
  uint32_t u = __float_as_uint(f);
  u += 0x7fffu + ((u >> 16) & 1u);   // round-to-nearest-even
  return (uint16_t)(u >> 16);
}

__device__ __forceinline__ void async_copy16(const uint16_t* src, uint16_t* lds_dst) {
  __builtin_amdgcn_global_load_lds(
      (const __attribute__((address_space(1))) void*)src,
      (__attribute__((address_space(3))) void*)lds_dst, 16, 0, 0);
}

// byte offset into a [rows][64] bf16 LDS tile with XOR swizzle (slot ^= row&7)
__device__ __forceinline__ int swz16(int row, int byte_in_row) {
  return row * 128 + (byte_in_row ^ ((row & 7) << 4));
}

// ===== packed fragment layout =====
// element (m,k) of a [rows][K] matrix lives at:
//   (((pm*steps + kk)*4 + i)*64 + lane)*8 + e
// pm=m>>6, i=(m>>4)&3, kk=k>>5, lane=((k>>3)&3)*16 + (m&15), e=k&7, steps=K>>5.

// ---------------- weight pack fp32 -> bf16 fragments (dest-coalesced) ----------------
__global__ __launch_bounds__(256)
void cvt_packB(const float* __restrict__ in, uint16_t* __restrict__ out,
               int K, int logsteps, int matsize) {
  const int lyr = blockIdx.y;
  const int t = blockIdx.x * 256 + threadIdx.x;   // octet id within matrix
  const int lane = t & 63;
  const int j = (t >> 6) & 3;
  const int kk = (t >> 8) & ((1 << logsteps) - 1);
  const int pn = t >> (8 + logsteps);
  const int n = pn * 64 + j * 16 + (lane & 15);
  const int k0 = (kk << 5) + (lane >> 4) * 8;
  const float* src = in + (size_t)lyr * matsize + (size_t)n * K + k0;
  const float4 v0 = *(const float4*)(src);
  const float4 v1 = *(const float4*)(src + 4);
  uint64_t p0 = (uint64_t)f2bf(v0.x) | ((uint64_t)f2bf(v0.y) << 16)
              | ((uint64_t)f2bf(v0.z) << 32) | ((uint64_t)f2bf(v0.w) << 48);
  uint64_t p1 = (uint64_t)f2bf(v1.x) | ((uint64_t)f2bf(v1.y) << 16)
              | ((uint64_t)f2bf(v1.z) << 32) | ((uint64_t)f2bf(v1.w) << 48);
  uint64_t* dst = (uint64_t*)(out + (size_t)lyr * matsize + (size_t)t * 8);
  dst[0] = p0; dst[1] = p1;
}

// ---------------- LayerNorm ----------------
// OUTMODE 1: fp32 row-major out. OUTMODE 2: bf16 packed-A out (K=1024, steps=32).
template<int OUTMODE>
__global__ __launch_bounds__(256)
void ln_fwd(const float* __restrict__ x, const float* __restrict__ w,
            const float* __restrict__ b, void* __restrict__ outp) {
  const int row = blockIdx.x;
  const int tid = threadIdx.x;
  const float4 v = reinterpret_cast<const float4*>(x + (size_t)row * C_)[tid];
  float s  = v.x + v.y + v.z + v.w;
  float s2 = v.x*v.x + v.y*v.y + v.z*v.z + v.w*v.w;
  #pragma unroll
  for (int d = 1; d < 64; d <<= 1) {
    s  += __shfl_xor(s, d);
    s2 += __shfl_xor(s2, d);
  }
  __shared__ float red[8];
  const int wv = tid >> 6;
  if ((tid & 63) == 0) { red[wv] = s; red[wv + 4] = s2; }
  __syncthreads();
  s  = red[0] + red[1] + red[2] + red[3];
  s2 = red[4] + red[5] + red[6] + red[7];
  const float mu = s * (1.0f / C_);
  const float rs = rsqrtf(fmaxf(s2 * (1.0f / C_) - mu * mu, 0.0f) + 1e-6f);
  const float4 wv4 = reinterpret_cast<const float4*>(w)[tid];
  const float4 bv4 = reinterpret_cast<const float4*>(b)[tid];
  const float o0 = (v.x - mu) * rs * wv4.x + bv4.x;
  const float o1 = (v.y - mu) * rs * wv4.y + bv4.y;
  const float o2 = (v.z - mu) * rs * wv4.z + bv4.z;
  const float o3 = (v.w - mu) * rs * wv4.w + bv4.w;
  if (OUTMODE == 2) {
    const int c0 = tid * 4;
    const int kk = c0 >> 5, l4p = (c0 >> 3) & 3, e0 = c0 & 7;   // e0 in {0,4}
    const int pm = row >> 6, ii = (row >> 4) & 3;
    const int lanep = l4p * 16 + (row & 15);
    const uint64_t pk = (uint64_t)f2bf(o0) | ((uint64_t)f2bf(o1) << 16)
                      | ((uint64_t)f2bf(o2) << 32) | ((uint64_t)f2bf(o3) << 48);
    uint16_t* op = (uint16_t*)outp;
    *(uint64_t*)(op + ((((size_t)pm * 32 + kk) * 4 + ii) * 64 + lanep) * 8 + e0) = pk;
  } else {
    float4 o; o.x = o0; o.y = o1; o.z = o2; o.w = o3;
    reinterpret_cast<float4*>((float*)outp + (size_t)row * C_)[tid] = o;
  }
}

// ---------------- register GEMM: C[m,n] = sum_k A[m,k]*W[n,k] (+ bias) ----------------
// No LDS, no barriers. A and B in packed-fragment layout. 128x128 block tile,
// 4 waves (2x2), wave-tile 64x64 (acc 4x4). launch_bounds(256,3): VGPR cap ~170
// so the 2-deep ld/mm ping-pong stays fully in registers.
// EPI 1: GELU(tanh-form) -> packed bf16 (outKsteps). EPI 3: fp32 partial -> pbuf[kc].
// EPI 4: qkv head-split (Q*0.125 -> Qp, K -> Kp, V -> VTp transposed).
template<int EPI, int SPLIT>
__global__ __launch_bounds__(256, 3)
void gemm_reg(const uint16_t* __restrict__ Apk, const uint16_t* __restrict__ Bpk,
              const float* __restrict__ bias, uint16_t* __restrict__ outb,
              float* __restrict__ pbuf, int Nn, int K, int outKsteps,
              uint16_t* __restrict__ Qp, uint16_t* __restrict__ Kp,
              uint16_t* __restrict__ VTp) {
  const int nwg = (int)gridDim.x;
  const int q8 = nwg >> 3, r8 = nwg & 7;
  const int xcd = (int)blockIdx.x & 7, pos = (int)blockIdx.x >> 3;
  const int wgid = (xcd < r8 ? xcd * (q8 + 1) : r8 * (q8 + 1) + (xcd - r8) * q8) + pos;
  const int NB = Nn >> 7;
  const int kc  = (SPLIT > 1) ? wgid / (GMB_ * NB) : 0;
  const int rem = (SPLIT > 1) ? wgid % (GMB_ * NB) : wgid;
  const int bn = rem / GMB_, bm = rem % GMB_;

  const int tid = (int)threadIdx.x;
  const int l = tid & 63, w = tid >> 6;
  const int l15 = l & 15, l4 = l >> 4;
  const int wr = w >> 1, wc = w & 1;
  const int steps = K >> 5;          // total k-steps in packed layout
  const int kcsteps = steps / SPLIT; // k-steps this block handles

  const uint16_t* Aw = Apk + ((size_t)(bm * 2 + wr) * steps + (size_t)kc * kcsteps) * 2048 + l * 8;
  const uint16_t* Bw = Bpk + ((size_t)(bn * 2 + wc) * steps + (size_t)kc * kcsteps) * 2048 + l * 8;

  f32x4 acc[4][4] = {};
  bf16x8 a0[4], b0[4], a1[4], b1[4];

  auto ld0 = [&](int s) {
    const uint16_t* ap = Aw + (size_t)s * 2048;
    const uint16_t* bp = Bw + (size_t)s * 2048;
    #pragma unroll
    for (int i = 0; i < 4; ++i) a0[i] = *(const bf16x8*)(ap + i * 512);
    #pragma unroll
    for (int j = 0; j < 4; ++j) b0[j] = *(const bf16x8*)(bp + j * 512);
  };
  auto ld1 = [&](int s) {
    const uint16_t* ap = Aw + (size_t)s * 2048;
    const uint16_t* bp = Bw + (size_t)s * 2048;
    #pragma unroll
    for (int i = 0; i < 4; ++i) a1[i] = *(const bf16x8*)(ap + i * 512);
    #pragma unroll
    for (int j = 0; j < 4; ++j) b1[j] = *(const bf16x8*)(bp + j * 512);
  };
  auto mm0 = [&] {
    #pragma unroll
    for (int i = 0; i < 4; ++i)
      #pragma unroll
      for (int j = 0; j < 4; ++j)
        acc[i][j] = __builtin_amdgcn_mfma_f32_16x16x32_bf16(a0[i], b0[j], acc[i][j], 0, 0, 0);
  };
  auto mm1 = [&] {
    #pragma unroll
    for (int i = 0; i < 4; ++i)
      #pragma unroll
      for (int j = 0; j < 4; ++j)
        acc[i][j] = __builtin_amdgcn_mfma_f32_16x16x32_bf16(a1[i], b1[j], acc[i][j], 0, 0, 0);
  };

  ld0(0);
  for (int s = 0; s + 2 <= kcsteps; s += 2) {
    ld1(s + 1);
    mm0();
    if (s + 2 < kcsteps) ld0(s + 2);
    mm1();
  }

  #pragma unroll
  for (int j = 0; j < 4; ++j) {
    const int col = bn * 128 + wc * 64 + j * 16 + l15;
    const float bv = (EPI == 3) ? 0.0f : bias[col];
    #pragma unroll
    for (int i = 0; i < 4; ++i) {
      const int mb = bm * 128 + wr * 64 + i * 16 + l4 * 4;
      #pragma unroll
      for (int r = 0; r < 4; ++r) {
        const int m = mb + r;
        const float v = acc[i][j][r] + bv;
        if (EPI == 1) {
          // tanh-form GELU: x * sigmoid(1.5957691*(x + 0.044715 x^3)); max err ~5e-4
          const float u = -1.5957691216f * (v + 0.044715f * v * v * v);
          const float g = v * __builtin_amdgcn_rcpf(1.0f + __expf(u));
          const int pm = m >> 6, ii = (m >> 4) & 3;
          const int kk = col >> 5, l4p = (col >> 3) & 3, e = col & 7;
          const int lanep = l4p * 16 + (m & 15);
          outb[((((size_t)pm * outKsteps + kk) * 4 + ii) * 64 + lanep) * 8 + e] = f2bf(g);
        } else if (EPI == 3) {
          pbuf[((size_t)kc * MP2_ + m) * C_ + col] = v;
        } else {  // EPI == 4: qkv split into per-head panels
          if (m < M_TOK) {
            const int which = col >> 10;          // 0=Q, 1=K, 2=V
            const int h = (col >> 6) & 15;
            const int d = col & 63;
            const int b = m / N_TOK;
            const int key = m - b * N_TOK;
            const int bh = b * 16 + h;
            if (which == 0)      Qp[((size_t)bh * KPAD_ + key) * 64 + d] = f2bf(v * 0.125f);
            else if (which == 1) Kp[((size_t)bh * KPAD_ + key) * 64 + d] = f2bf(v);
            else                 VTp[((size_t)bh * 64 + d) * KPAD_ + key] = f2bf(v);
          }
        }
      }
    }
  }
}

// ---------------- split-K reduce: xbuf[m,:] += bias + sum_kc pbuf[kc,m,:] ----------------
template<int KCH>
__global__ __launch_bounds__(256)
void reduce_add(const float* __restrict__ pbuf, const float* __restrict__ bias,
                float* __restrict__ xbuf) {
  const int m = blockIdx.x;          // < M_TOK
  const int c4 = threadIdx.x;        // 256 * float4 = 1024 cols
  float4 s = reinterpret_cast<const float4*>(bias)[c4];
  #pragma unroll
  for (int kc = 0; kc < KCH; ++kc) {
    const float4 pv = reinterpret_cast<const float4*>(pbuf + ((size_t)kc * MP2_ + m) * C_)[c4];
    s.x += pv.x; s.y += pv.y; s.z += pv.z; s.w += pv.w;
  }
  float4 x = reinterpret_cast<float4*>(xbuf + (size_t)m * C_)[c4];
  x.x += s.x; x.y += s.y; x.z += s.z; x.w += s.w;
  reinterpret_cast<float4*>(xbuf + (size_t)m * C_)[c4] = x;
}

// ---------------- Flash attention (swapped operands, q lane-local) ----------------
// Qp/Kp: [bh][KPAD_][64] (Q pre-scaled by 0.125). VTp: [bh][64][KPAD_].
// Output: packed-A bf16 (K=1024, steps=32) into hbuf.
__global__ __launch_bounds__(256, 3)
void attn_fwd(const uint16_t* __restrict__ Qp, const uint16_t* __restrict__ Kp,
              const uint16_t* __restrict__ VTp, uint16_t* __restrict__ ob) {
  __shared__ uint16_t Ksm_[KVB_ * 64];     // [key][d], swizzled slots
  __shared__ uint16_t Vsm_[64 * KVB_];     // [d][key], swizzled slots
  __shared__ uint16_t Psm_[4][16 * 136];   // per wave: [q=16][keys 128 + pad]

  const int tid = (int)threadIdx.x;
  const int l = tid & 63, w = tid >> 6;
  const int l15 = l & 15, l4 = l >> 4;
  const int bh = (int)blockIdx.x;
  const int qt = (int)blockIdx.y;

  const uint16_t* Kb = Kp + (size_t)bh * KPAD_ * 64;
  const uint16_t* Vb = VTp + (size_t)bh * 64 * KPAD_;

  // Q fragments: B-operand, lane l15 = q-row
  bf16x8 qf[2];
  {
    const int qrow = qt * 64 + w * 16 + l15;
    const uint16_t* qbase = Qp + ((size_t)bh * KPAD_ + qrow) * 64;
    qf[0] = *(const bf16x8*)(qbase + l4 * 8);
    qf[1] = *(const bf16x8*)(qbase + 32 + l4 * 8);
  }

  float mrow = -1e30f, lrow = 0.0f;
  f32x4 oacc[4] = {};

  const int krow_s = tid >> 3;                    // 0..31
  const int kslot_s = (tid & 7) ^ (krow_s & 7);
  const int vd_s = tid >> 4;                      // 0..15
  const int vslot_s = (tid & 15) ^ (vd_s & 15);

  for (int kt = 0; kt < KVT2_; ++kt) {
    const int key0 = kt * KVB_;
    __syncthreads();   // prev tile reads done
    #pragma unroll
    for (int it = 0; it < 4; ++it) {
      const int row = it * 32 + krow_s;
      async_copy16(Kb + (size_t)(key0 + row) * 64 + kslot_s * 8,
                   Ksm_ + it * 2048 + tid * 8);
    }
    #pragma unroll
    for (int it = 0; it < 4; ++it) {
      const int d = it * 16 + vd_s;
      async_copy16(Vb + (size_t)d * KPAD_ + key0 + vslot_s * 8,
                   Vsm_ + it * 2048 + tid * 8);
    }
    __syncthreads();   // staged

    // S^T: s[kf][r] = S[key0 + kf*16 + l4*4 + r][q = l15]
    f32x4 s[8];
    #pragma unroll
    for (int kf = 0; kf < 8; ++kf) s[kf] = f32x4{0.f, 0.f, 0.f, 0.f};
    #pragma unroll
    for (int kk = 0; kk < 2; ++kk) {
      #pragma unroll
      for (int kf = 0; kf < 8; ++kf) {
        const bf16x8 kfrag = *(const bf16x8*)((const char*)Ksm_ + swz16(kf * 16 + l15, kk * 64 + l4 * 16));
        s[kf] = __builtin_amdgcn_mfma_f32_16x16x32_bf16(kfrag, qf[kk], s[kf], 0, 0, 0);
      }
    }
    // mask tail keys
    if (kt == KVT2_ - 1) {
      #pragma unroll
      for (int kf = 0; kf < 8; ++kf)
        #pragma unroll
        for (int r = 0; r < 4; ++r)
          if (key0 + kf * 16 + l4 * 4 + r >= N_TOK) s[kf][r] = -1e30f;
    }
    // row max (31 register fmax + 2 shfl)
    float pmx = s[0][0];
    #pragma unroll
    for (int kf = 0; kf < 8; ++kf)
      #pragma unroll
      for (int r = 0; r < 4; ++r) pmx = fmaxf(pmx, s[kf][r]);
    pmx = fmaxf(pmx, __shfl_xor(pmx, 16));
    pmx = fmaxf(pmx, __shfl_xor(pmx, 32));
    // defer-max (T13)
    if (!__all(pmx - mrow <= 8.0f)) {
      const float mi = fmaxf(mrow, pmx);
      const float sc = __expf(mrow - mi);
      mrow = mi;
      lrow *= sc;
      #pragma unroll
      for (int df = 0; df < 4; ++df)
        #pragma unroll
        for (int r = 0; r < 4; ++r) oacc[df][r] *= sc;
    }
    // P = exp(s - m); pack 4 keys -> one b64 LDS write per kf
    float psum = 0.0f;
    #pragma unroll
    for (int kf = 0; kf < 8; ++kf) {
      const float p0 = __expf(s[kf][0] - mrow);
      const float p1 = __expf(s[kf][1] - mrow);
      const float p2 = __expf(s[kf][2] - mrow);
      const float p3 = __expf(s[kf][3] - mrow);
      psum += (p0 + p1) + (p2 + p3);
      const uint64_t pk = (uint64_t)f2bf(p0) | ((uint64_t)f2bf(p1) << 16)
                        | ((uint64_t)f2bf(p2) << 32) | ((uint64_t)f2bf(p3) << 48);
      *(uint64_t*)(&Psm_[w][l15 * 136 + kf * 16 + l4 * 4]) = pk;
    }
    psum += __shfl_xor(psum, 16);
    psum += __shfl_xor(psum, 32);
    lrow += psum;
    // O^T += V^T P : oacc[df][r] = O[d = df*16 + l4*4 + r][q = l15]
    #pragma unroll
    for (int kk = 0; kk < 4; ++kk) {
      const bf16x8 pf = *(const bf16x8*)(&Psm_[w][l15 * 136 + kk * 32 + l4 * 8]);
      #pragma unroll
      for (int df = 0; df < 4; ++df) {
        const int d = df * 16 + l15;
        const bf16x8 vfrag = *(const bf16x8*)(Vsm_ + d * KVB_ + (((kk * 4 + l4) ^ (d & 15)) * 8));
        oacc[df] = __builtin_amdgcn_mfma_f32_16x16x32_bf16(vfrag, pf, oacc[df], 0, 0, 0);
      }
    }
  }

  // store: O[d][q=l15] -> packed-A layout (K=1024, steps=32)
  const int q = qt * 64 + w * 16 + l15;
  if (q < N_TOK) {
    const float inv = 1.0f / lrow;
    const int m = (bh >> 4) * N_TOK + q;
    const int pmq = m >> 6, ii = (m >> 4) & 3, m15 = m & 15;
    const int hbase = (bh & 15) * 64;
    #pragma unroll
    for (int df = 0; df < 4; ++df)
      #pragma unroll
      for (int r = 0; r < 4; ++r) {
        const int c = hbase + df * 16 + l4 * 4 + r;
        const int kkp = c >> 5, l4p = (c >> 3) & 3, e = c & 7;
        ob[((((size_t)pmq * 32 + kkp) * 4 + ii) * 64 + l4p * 16 + m15) * 8 + e] =
            f2bf(oacc[df][r] * inv);
      }
  }
}

extern "C" void kernel_launch(void* const* d_in, const int* in_sizes, int n_in,
                              void* d_out, int out_size, void* d_ws, size_t ws_size,
                              hipStream_t stream) {
  const float* x_in   = (const float*)d_in[0];
  const float* ln1_w  = (const float*)d_in[1];
  const float* ln1_b  = (const float*)d_in[2];
  const float* qkv_w  = (const float*)d_in[3];
  const float* qkv_b  = (const float*)d_in[4];
  const float* proj_w = (const float*)d_in[5];
  const float* proj_b = (const float*)d_in[6];
  const float* ln2_w  = (const float*)d_in[7];
  const float* ln2_b  = (const float*)d_in[8];
  const float* fc1_w  = (const float*)d_in[9];
  const float* fc1_b  = (const float*)d_in[10];
  const float* fc2_w  = (const float*)d_in[11];
  const float* fc2_b  = (const float*)d_in[12];
  const float* norm_w = (const float*)d_in[13];
  const float* norm_b = (const float*)d_in[14];

  char* p = (char*)d_ws;
  float*    xbuf = (float*)p;     p += (size_t)MP2_ * C_ * 4;
  uint16_t* hbuf = (uint16_t*)p;  p += (size_t)MP2_ * C_ * 2;   // packed A: LN out / attn out
  uint16_t* big  = (uint16_t*)p;  p += (size_t)MP2_ * HID_ * 2; // fc1 packed out
  uint16_t* wq   = (uint16_t*)p;  p += (size_t)L_ * 3 * C_ * C_ * 2;
  uint16_t* wp   = (uint16_t*)p;  p += (size_t)L_ * C_ * C_ * 2;
  uint16_t* w1   = (uint16_t*)p;  p += (size_t)L_ * HID_ * C_ * 2;
  uint16_t* w2   = (uint16_t*)p;  p += (size_t)L_ * C_ * HID_ * 2;
  uint16_t* qp   = (uint16_t*)p;  p += (size_t)64 * KPAD_ * 64 * 2;
  uint16_t* kp   = (uint16_t*)p;  p += (size_t)64 * KPAD_ * 64 * 2;
  uint16_t* vtp  = (uint16_t*)p;  p += (size_t)64 * 64 * KPAD_ * 2;
  float*    pbuf = (float*)p;     p += (size_t)2 * MP2_ * C_ * 4;   // split-K partials
  if ((size_t)(p - (char*)d_ws) > ws_size) return;  // fail loudly (output stays poisoned)

  hipMemcpyAsync(xbuf, x_in, (size_t)M_TOK * C_ * sizeof(float),
                 hipMemcpyDeviceToDevice, stream);

  // pack weights into fragment order (once per call)
  cvt_packB<<<dim3(3 * C_ * C_ / 2048, L_), dim3(256), 0, stream>>>(qkv_w,  wq, C_,   5, 3 * C_ * C_);
  cvt_packB<<<dim3(C_ * C_ / 2048, L_),     dim3(256), 0, stream>>>(proj_w, wp, C_,   5, C_ * C_);
  cvt_packB<<<dim3(HID_ * C_ / 2048, L_),   dim3(256), 0, stream>>>(fc1_w,  w1, C_,   5, HID_ * C_);
  cvt_packB<<<dim3(C_ * HID_ / 2048, L_),   dim3(256), 0, stream>>>(fc2_w,  w2, HID_, 7, C_ * HID_);

  for (int lyr = 0; lyr < L_; ++lyr) {
    ln_fwd<2><<<dim3(M_TOK), dim3(256), 0, stream>>>(
        xbuf, ln1_w + (size_t)lyr * C_, ln1_b + (size_t)lyr * C_, hbuf);
    // qkv -> per-head panels (Q scaled)
    gemm_reg<4, 1><<<dim3((3 * C_ / 128) * GMB_), dim3(256), 0, stream>>>(
        hbuf, wq + (size_t)lyr * 3 * C_ * C_, qkv_b + (size_t)lyr * 3 * C_,
        nullptr, nullptr, 3 * C_, C_, 0, qp, kp, vtp);
    attn_fwd<<<dim3(64, 17), dim3(256), 0, stream>>>(qp, kp, vtp, hbuf);
    // proj: split-K x2 -> partials -> reduce (+bias +residual)
    gemm_reg<3, 2><<<dim3(2 * (C_ / 128) * GMB_), dim3(256), 0, stream>>>(
        hbuf, wp + (size_t)lyr * C_ * C_, nullptr,
        nullptr, pbuf, C_, C_, 0, nullptr, nullptr, nullptr);
    reduce_add<2><<<dim3(M_TOK), dim3(256), 0, stream>>>(
        pbuf, proj_b + (size_t)lyr * C_, xbuf);
    ln_fwd<2><<<dim3(M_TOK), dim3(256), 0, stream>>>(
        xbuf, ln2_w + (size_t)lyr * C_, ln2_b + (size_t)lyr * C_, hbuf);
    // fc1: fast GELU -> packed A for fc2
    gemm_reg<1, 1><<<dim3((HID_ / 128) * GMB_), dim3(256), 0, stream>>>(
        hbuf, w1 + (size_t)lyr * HID_ * C_, fc1_b + (size_t)lyr * HID_,
        big, nullptr, HID_, C_, HID_ >> 5, nullptr, nullptr, nullptr);
    // fc2: split-K x2 -> partials -> reduce (+bias +residual)
    gemm_reg<3, 2><<<dim3(2 * (C_ / 128) * GMB_), dim3(256), 0, stream>>>(
        big, w2 + (size_t)lyr * C_ * HID_, nullptr,
        nullptr, pbuf, C_, HID_, 0, nullptr, nullptr, nullptr);
    reduce_add<2><<<dim3(M_TOK), dim3(256), 0, stream>>>(
        pbuf, fc2_b + (size_t)lyr * C_, xbuf);
  }
  ln_fwd<1><<<dim3(M_TOK), dim3(256), 0, stream>>>(xbuf, norm_w, norm_b, d_out);
}

// Round 8
// 2752.416 us; speedup vs baseline: 1.3619x; 1.0156x over previous
//
#include <hip/hip_runtime.h>
#include <cstdint>
#include <cstddef>

#define B_    4
#define N_TOK 1029
#define C_    1024
#define H_    16
#define DH_   64
#define L_    8
#define HID_  4096
#define M_TOK (B_*N_TOK)   // 4116
#define MP2_  4352         // 34 * 128
#define GMB_  34           // m tiles of 128
#define KVB_  128
#define KVT2_ 9            // ceil(1029/128)
#define KPAD_ 1152         // 9*128

typedef float f32x4 __attribute__((ext_vector_type(4)));
typedef short bf16x8 __attribute__((ext_vector_type(8)));

__device__ __forceinline__ uint16_t f2bf(float f) {
  uint32_t u = __float_as_uint(f);
  u += 0x7fffu + ((u >> 16) & 1u);   // round-to-nearest-even
  return (uint16_t)(u >> 16);
}

__device__ __forceinline__ void async_copy16(const uint16_t* src, uint16_t* lds_dst) {
  __builtin_amdgcn_global_load_lds(
      (const __attribute__((address_space(1))) void*)src,
      (__attribute__((address_space(3))) void*)lds_dst, 16, 0, 0);
}

// byte offset into a [rows][64] bf16 LDS tile with XOR swizzle (slot ^= row&7)
__device__ __forceinline__ int swz16(int row, int byte_in_row) {
  return row * 128 + (byte_in_row ^ ((row & 7) << 4));
}

// ===== packed fragment layout =====
// element (m,k) of a [rows][K] matrix lives at:
//   (((pm*steps + kk)*4 + i)*64 + lane)*8 + e
// pm=m>>6, i=(m>>4)&3, kk=k>>5, lane=((k>>3)&3)*16 + (m&15), e=k&7, steps=K>>5.

// ---- asm load: compiler cannot see the VMEM counter -> we own vmcnt ----
#define GLD(dst, addr, OFF) \
  asm volatile("global_load_dwordx4 %0, %1, off offset:" OFF \
               : "=v"(dst) : "v"(addr))
#define VMCNT8 do { asm volatile("s_waitcnt vmcnt(8)" ::: "memory"); \
                    __builtin_amdgcn_sched_barrier(0); } while (0)
#define VMCNT0 do { asm volatile("s_waitcnt vmcnt(0)" ::: "memory"); \
                    __builtin_amdgcn_sched_barrier(0); } while (0)

__device__ __forceinline__ void issue8(bf16x8 (&A)[4], bf16x8 (&Bv)[4],
                                       const char* ap, const char* bp) {
  GLD(A[0], ap, "0");    GLD(A[1], ap, "1024");
  GLD(A[2], ap, "2048"); GLD(A[3], ap, "3072");
  GLD(Bv[0], bp, "0");    GLD(Bv[1], bp, "1024");
  GLD(Bv[2], bp, "2048"); GLD(Bv[3], bp, "3072");
}

__device__ __forceinline__ void mm16(f32x4 (&acc)[4][4], const bf16x8 (&A)[4],
                                     const bf16x8 (&Bv)[4]) {
#pragma unroll
  for (int i = 0; i < 4; ++i)
#pragma unroll
    for (int j = 0; j < 4; ++j)
      acc[i][j] = __builtin_amdgcn_mfma_f32_16x16x32_bf16(A[i], Bv[j], acc[i][j], 0, 0, 0);
}

// ---------------- weight pack fp32 -> bf16 fragments (dest-coalesced) ----------------
__global__ __launch_bounds__(256)
void cvt_packB(const float* __restrict__ in, uint16_t* __restrict__ out,
               int K, int logsteps, int matsize) {
  const int lyr = blockIdx.y;
  const int t = blockIdx.x * 256 + threadIdx.x;   // octet id within matrix
  const int lane = t & 63;
  const int j = (t >> 6) & 3;
  const int kk = (t >> 8) & ((1 << logsteps) - 1);
  const int pn = t >> (8 + logsteps);
  const int n = pn * 64 + j * 16 + (lane & 15);
  const int k0 = (kk << 5) + (lane >> 4) * 8;
  const float* src = in + (size_t)lyr * matsize + (size_t)n * K + k0;
  const float4 v0 = *(const float4*)(src);
  const float4 v1 = *(const float4*)(src + 4);
  uint64_t p0 = (uint64_t)f2bf(v0.x) | ((uint64_t)f2bf(v0.y) << 16)
              | ((uint64_t)f2bf(v0.z) << 32) | ((uint64_t)f2bf(v0.w) << 48);
  uint64_t p1 = (uint64_t)f2bf(v1.x) | ((uint64_t)f2bf(v1.y) << 16)
              | ((uint64_t)f2bf(v1.z) << 32) | ((uint64_t)f2bf(v1.w) << 48);
  uint64_t* dst = (uint64_t*)(out + (size_t)lyr * matsize + (size_t)t * 8);
  dst[0] = p0; dst[1] = p1;
}

// ---------------- LayerNorm ----------------
// OUTMODE 1: fp32 row-major out. OUTMODE 2: bf16 packed-A out (K=1024, steps=32).
template<int OUTMODE>
__global__ __launch_bounds__(256)
void ln_fwd(const float* __restrict__ x, const float* __restrict__ w,
            const float* __restrict__ b, void* __restrict__ outp) {
  const int row = blockIdx.x;
  const int tid = threadIdx.x;
  const float4 v = reinterpret_cast<const float4*>(x + (size_t)row * C_)[tid];
  float s  = v.x + v.y + v.z + v.w;
  float s2 = v.x*v.x + v.y*v.y + v.z*v.z + v.w*v.w;
  #pragma unroll
  for (int d = 1; d < 64; d <<= 1) {
    s  += __shfl_xor(s, d);
    s2 += __shfl_xor(s2, d);
  }
  __shared__ float red[8];
  const int wv = tid >> 6;
  if ((tid & 63) == 0) { red[wv] = s; red[wv + 4] = s2; }
  __syncthreads();
  s  = red[0] + red[1] + red[2] + red[3];
  s2 = red[4] + red[5] + red[6] + red[7];
  const float mu = s * (1.0f / C_);
  const float rs = rsqrtf(fmaxf(s2 * (1.0f / C_) - mu * mu, 0.0f) + 1e-6f);
  const float4 wv4 = reinterpret_cast<const float4*>(w)[tid];
  const float4 bv4 = reinterpret_cast<const float4*>(b)[tid];
  const float o0 = (v.x - mu) * rs * wv4.x + bv4.x;
  const float o1 = (v.y - mu) * rs * wv4.y + bv4.y;
  const float o2 = (v.z - mu) * rs * wv4.z + bv4.z;
  const float o3 = (v.w - mu) * rs * wv4.w + bv4.w;
  if (OUTMODE == 2) {
    const int c0 = tid * 4;
    const int kk = c0 >> 5, l4p = (c0 >> 3) & 3, e0 = c0 & 7;   // e0 in {0,4}
    const int pm = row >> 6, ii = (row >> 4) & 3;
    const int lanep = l4p * 16 + (row & 15);
    const uint64_t pk = (uint64_t)f2bf(o0) | ((uint64_t)f2bf(o1) << 16)
                      | ((uint64_t)f2bf(o2) << 32) | ((uint64_t)f2bf(o3) << 48);
    uint16_t* op = (uint16_t*)outp;
    *(uint64_t*)(op + ((((size_t)pm * 32 + kk) * 4 + ii) * 64 + lanep) * 8 + e0) = pk;
  } else {
    float4 o; o.x = o0; o.y = o1; o.z = o2; o.w = o3;
    reinterpret_cast<float4*>((float*)outp + (size_t)row * C_)[tid] = o;
  }
}

// ---------------- register GEMM, hand-pipelined (asm loads + counted vmcnt) ----------
// C[m,n] = sum_k A[m,k]*W[n,k] (+ bias). No LDS, no barriers. Packed-fragment
// operands; 128x128 block tile, 4 waves (2x2), wave-tile 64x64 (acc 4x4).
// Steady state: 8-16 dwordx4 in flight, never drained below 8 until the tail.
// EPI 1: GELU(tanh-form) -> packed bf16 (outKsteps). EPI 2: fp32 resid +=.
// EPI 4: qkv head-split (Q*0.125 -> Qp, K -> Kp, V -> VTp transposed).
template<int EPI>
__global__ __launch_bounds__(256, 3)
void gemm_reg(const uint16_t* __restrict__ Apk, const uint16_t* __restrict__ Bpk,
              const float* __restrict__ bias, uint16_t* __restrict__ outb,
              float* __restrict__ resid, int Nn, int K, int outKsteps,
              uint16_t* __restrict__ Qp, uint16_t* __restrict__ Kp,
              uint16_t* __restrict__ VTp) {
  const int nwg = (int)gridDim.x;
  const int q8 = nwg >> 3, r8 = nwg & 7;
  const int xcd = (int)blockIdx.x & 7, pos = (int)blockIdx.x >> 3;
  const int wgid = (xcd < r8 ? xcd * (q8 + 1) : r8 * (q8 + 1) + (xcd - r8) * q8) + pos;
  const int bn = wgid / GMB_, bm = wgid % GMB_;

  const int tid = (int)threadIdx.x;
  const int l = tid & 63, w = tid >> 6;
  const int l15 = l & 15, l4 = l >> 4;
  const int wr = w >> 1, wc = w & 1;
  const int steps = K >> 5;

  const char* Abase = (const char*)(Apk + ((size_t)(bm * 2 + wr) * steps) * 2048 + l * 8);
  const char* Bbase = (const char*)(Bpk + ((size_t)(bn * 2 + wc) * steps) * 2048 + l * 8);

  f32x4 acc[4][4] = {};
  bf16x8 a0[4], b0[4], a1[4], b1[4];

  issue8(a0, b0, Abase, Bbase);
  issue8(a1, b1, Abase + 4096, Bbase + 4096);
  int s = 0;
  for (; s + 4 <= steps; s += 2) {
    VMCNT8;
    mm16(acc, a0, b0);
    issue8(a0, b0, Abase + (size_t)(s + 2) * 4096, Bbase + (size_t)(s + 2) * 4096);
    VMCNT8;
    mm16(acc, a1, b1);
    issue8(a1, b1, Abase + (size_t)(s + 3) * 4096, Bbase + (size_t)(s + 3) * 4096);
  }
  VMCNT8;
  mm16(acc, a0, b0);
  VMCNT0;
  mm16(acc, a1, b1);

  #pragma unroll
  for (int j = 0; j < 4; ++j) {
    const int col = bn * 128 + wc * 64 + j * 16 + l15;
    const float bv = bias[col];
    #pragma unroll
    for (int i = 0; i < 4; ++i) {
      const int mb = bm * 128 + wr * 64 + i * 16 + l4 * 4;
      #pragma unroll
      for (int r = 0; r < 4; ++r) {
        const int m = mb + r;
        const float v = acc[i][j][r] + bv;
        if (EPI == 1) {
          // tanh-form GELU: x * sigmoid(1.5957691*(x + 0.044715 x^3)); max err ~5e-4
          const float u = -1.5957691216f * (v + 0.044715f * v * v * v);
          const float g = v * __builtin_amdgcn_rcpf(1.0f + __expf(u));
          const int pm = m >> 6, ii = (m >> 4) & 3;
          const int kk = col >> 5, l4p = (col >> 3) & 3, e = col & 7;
          const int lanep = l4p * 16 + (m & 15);
          outb[((((size_t)pm * outKsteps + kk) * 4 + ii) * 64 + lanep) * 8 + e] = f2bf(g);
        } else if (EPI == 2) {
          if (m < M_TOK) resid[(size_t)m * Nn + col] += v;
        } else {  // EPI == 4: qkv split into per-head panels
          if (m < M_TOK) {
            const int which = col >> 10;          // 0=Q, 1=K, 2=V
            const int h = (col >> 6) & 15;
            const int d = col & 63;
            const int b = m / N_TOK;
            const int key = m - b * N_TOK;
            const int bh = b * 16 + h;
            if (which == 0)      Qp[((size_t)bh * KPAD_ + key) * 64 + d] = f2bf(v * 0.125f);
            else if (which == 1) Kp[((size_t)bh * KPAD_ + key) * 64 + d] = f2bf(v);
            else                 VTp[((size_t)bh * 64 + d) * KPAD_ + key] = f2bf(v);
          }
        }
      }
    }
  }
}

// ---------------- Flash attention (swapped operands, q lane-local) ----------------
// Qp/Kp: [bh][KPAD_][64] (Q pre-scaled by 0.125). VTp: [bh][64][KPAD_].
// Output: packed-A bf16 (K=1024, steps=32) into hbuf.
__global__ __launch_bounds__(256, 3)
void attn_fwd(const uint16_t* __restrict__ Qp, const uint16_t* __restrict__ Kp,
              const uint16_t* __restrict__ VTp, uint16_t* __restrict__ ob) {
  __shared__ uint16_t Ksm_[KVB_ * 64];     // [key][d], swizzled slots
  __shared__ uint16_t Vsm_[64 * KVB_];     // [d][key], swizzled slots
  __shared__ uint16_t Psm_[4][16 * 136];   // per wave: [q=16][keys 128 + pad]

  const int tid = (int)threadIdx.x;
  const int l = tid & 63, w = tid >> 6;
  const int l15 = l & 15, l4 = l >> 4;
  const int bh = (int)blockIdx.x;
  const int qt = (int)blockIdx.y;

  const uint16_t* Kb = Kp + (size_t)bh * KPAD_ * 64;
  const uint16_t* Vb = VTp + (size_t)bh * 64 * KPAD_;

  // Q fragments: B-operand, lane l15 = q-row
  bf16x8 qf[2];
  {
    const int qrow = qt * 64 + w * 16 + l15;
    const uint16_t* qbase = Qp + ((size_t)bh * KPAD_ + qrow) * 64;
    qf[0] = *(const bf16x8*)(qbase + l4 * 8);
    qf[1] = *(const bf16x8*)(qbase + 32 + l4 * 8);
  }

  float mrow = -1e30f, lrow = 0.0f;
  f32x4 oacc[4] = {};

  const int krow_s = tid >> 3;                    // 0..31
  const int kslot_s = (tid & 7) ^ (krow_s & 7);
  const int vd_s = tid >> 4;                      // 0..15
  const int vslot_s = (tid & 15) ^ (vd_s & 15);

  for (int kt = 0; kt < KVT2_; ++kt) {
    const int key0 = kt * KVB_;
    __syncthreads();   // prev tile reads done
    #pragma unroll
    for (int it = 0; it < 4; ++it) {
      const int row = it * 32 + krow_s;
      async_copy16(Kb + (size_t)(key0 + row) * 64 + kslot_s * 8,
                   Ksm_ + it * 2048 + tid * 8);
    }
    #pragma unroll
    for (int it = 0; it < 4; ++it) {
      const int d = it * 16 + vd_s;
      async_copy16(Vb + (size_t)d * KPAD_ + key0 + vslot_s * 8,
                   Vsm_ + it * 2048 + tid * 8);
    }
    __syncthreads();   // staged

    // S^T: s[kf][r] = S[key0 + kf*16 + l4*4 + r][q = l15]
    f32x4 s[8];
    #pragma unroll
    for (int kf = 0; kf < 8; ++kf) s[kf] = f32x4{0.f, 0.f, 0.f, 0.f};
    #pragma unroll
    for (int kk = 0; kk < 2; ++kk) {
      #pragma unroll
      for (int kf = 0; kf < 8; ++kf) {
        const bf16x8 kfrag = *(const bf16x8*)((const char*)Ksm_ + swz16(kf * 16 + l15, kk * 64 + l4 * 16));
        s[kf] = __builtin_amdgcn_mfma_f32_16x16x32_bf16(kfrag, qf[kk], s[kf], 0, 0, 0);
      }
    }
    // mask tail keys
    if (kt == KVT2_ - 1) {
      #pragma unroll
      for (int kf = 0; kf < 8; ++kf)
        #pragma unroll
        for (int r = 0; r < 4; ++r)
          if (key0 + kf * 16 + l4 * 4 + r >= N_TOK) s[kf][r] = -1e30f;
    }
    // row max (31 register fmax + 2 shfl)
    float pmx = s[0][0];
    #pragma unroll
    for (int kf = 0; kf < 8; ++kf)
      #pragma unroll
      for (int r = 0; r < 4; ++r) pmx = fmaxf(pmx, s[kf][r]);
    pmx = fmaxf(pmx, __shfl_xor(pmx, 16));
    pmx = fmaxf(pmx, __shfl_xor(pmx, 32));
    // defer-max (T13)
    if (!__all(pmx - mrow <= 8.0f)) {
      const float mi = fmaxf(mrow, pmx);
      const float sc = __expf(mrow - mi);
      mrow = mi;
      lrow *= sc;
      #pragma unroll
      for (int df = 0; df < 4; ++df)
        #pragma unroll
        for (int r = 0; r < 4; ++r) oacc[df][r] *= sc;
    }
    // P = exp(s - m); pack 4 keys -> one b64 LDS write per kf
    float psum = 0.0f;
    #pragma unroll
    for (int kf = 0; kf < 8; ++kf) {
      const float p0 = __expf(s[kf][0] - mrow);
      const float p1 = __expf(s[kf][1] - mrow);
      const float p2 = __expf(s[kf][2] - mrow);
      const float p3 = __expf(s[kf][3] - mrow);
      psum += (p0 + p1) + (p2 + p3);
      const uint64_t pk = (uint64_t)f2bf(p0) | ((uint64_t)f2bf(p1) << 16)
                        | ((uint64_t)f2bf(p2) << 32) | ((uint64_t)f2bf(p3) << 48);
      *(uint64_t*)(&Psm_[w][l15 * 136 + kf * 16 + l4 * 4]) = pk;
    }
    psum += __shfl_xor(psum, 16);
    psum += __shfl_xor(psum, 32);
    lrow += psum;
    // O^T += V^T P : oacc[df][r] = O[d = df*16 + l4*4 + r][q = l15]
    #pragma unroll
    for (int kk = 0; kk < 4; ++kk) {
      const bf16x8 pf = *(const bf16x8*)(&Psm_[w][l15 * 136 + kk * 32 + l4 * 8]);
      #pragma unroll
      for (int df = 0; df < 4; ++df) {
        const int d = df * 16 + l15;
        const bf16x8 vfrag = *(const bf16x8*)(Vsm_ + d * KVB_ + (((kk * 4 + l4) ^ (d & 15)) * 8));
        oacc[df] = __builtin_amdgcn_mfma_f32_16x16x32_bf16(vfrag, pf, oacc[df], 0, 0, 0);
      }
    }
  }

  // store: O[d][q=l15] -> packed-A layout (K=1024, steps=32)
  const int q = qt * 64 + w * 16 + l15;
  if (q < N_TOK) {
    const float inv = 1.0f / lrow;
    const int m = (bh >> 4) * N_TOK + q;
    const int pmq = m >> 6, ii = (m >> 4) & 3, m15 = m & 15;
    const int hbase = (bh & 15) * 64;
    #pragma unroll
    for (int df = 0; df < 4; ++df)
      #pragma unroll
      for (int r = 0; r < 4; ++r) {
        const int c = hbase + df * 16 + l4 * 4 + r;
        const int kkp = c >> 5, l4p = (c >> 3) & 3, e = c & 7;
        ob[((((size_t)pmq * 32 + kkp) * 4 + ii) * 64 + l4p * 16 + m15) * 8 + e] =
            f2bf(oacc[df][r] * inv);
      }
  }
}

extern "C" void kernel_launch(void* const* d_in, const int* in_sizes, int n_in,
                              void* d_out, int out_size, void* d_ws, size_t ws_size,
                              hipStream_t stream) {
  const float* x_in   = (const float*)d_in[0];
  const float* ln1_w  = (const float*)d_in[1];
  const float* ln1_b  = (const float*)d_in[2];
  const float* qkv_w  = (const float*)d_in[3];
  const float* qkv_b  = (const float*)d_in[4];
  const float* proj_w = (const float*)d_in[5];
  const float* proj_b = (const float*)d_in[6];
  const float* ln2_w  = (const float*)d_in[7];
  const float* ln2_b  = (const float*)d_in[8];
  const float* fc1_w  = (const float*)d_in[9];
  const float* fc1_b  = (const float*)d_in[10];
  const float* fc2_w  = (const float*)d_in[11];
  const float* fc2_b  = (const float*)d_in[12];
  const float* norm_w = (const float*)d_in[13];
  const float* norm_b = (const float*)d_in[14];

  char* p = (char*)d_ws;
  float*    xbuf = (float*)p;     p += (size_t)MP2_ * C_ * 4;
  uint16_t* hbuf = (uint16_t*)p;  p += (size_t)MP2_ * C_ * 2;   // packed A: LN out / attn out
  uint16_t* big  = (uint16_t*)p;  p += (size_t)MP2_ * HID_ * 2; // fc1 packed out
  uint16_t* wq   = (uint16_t*)p;  p += (size_t)L_ * 3 * C_ * C_ * 2;
  uint16_t* wp   = (uint16_t*)p;  p += (size_t)L_ * C_ * C_ * 2;
  uint16_t* w1   = (uint16_t*)p;  p += (size_t)L_ * HID_ * C_ * 2;
  uint16_t* w2   = (uint16_t*)p;  p += (size_t)L_ * C_ * HID_ * 2;
  uint16_t* qp   = (uint16_t*)p;  p += (size_t)64 * KPAD_ * 64 * 2;
  uint16_t* kp   = (uint16_t*)p;  p += (size_t)64 * KPAD_ * 64 * 2;
  uint16_t* vtp  = (uint16_t*)p;  p += (size_t)64 * 64 * KPAD_ * 2;
  if ((size_t)(p - (char*)d_ws) > ws_size) return;  // fail loudly (output stays poisoned)

  hipMemcpyAsync(xbuf, x_in, (size_t)M_TOK * C_ * sizeof(float),
                 hipMemcpyDeviceToDevice, stream);

  // pack weights into fragment order (once per call)
  cvt_packB<<<dim3(3 * C_ * C_ / 2048, L_), dim3(256), 0, stream>>>(qkv_w,  wq, C_,   5, 3 * C_ * C_);
  cvt_packB<<<dim3(C_ * C_ / 2048, L_),     dim3(256), 0, stream>>>(proj_w, wp, C_,   5, C_ * C_);
  cvt_packB<<<dim3(HID_ * C_ / 2048, L_),   dim3(256), 0, stream>>>(fc1_w,  w1, C_,   5, HID_ * C_);
  cvt_packB<<<dim3(C_ * HID_ / 2048, L_),   dim3(256), 0, stream>>>(fc2_w,  w2, HID_, 7, C_ * HID_);

  for (int lyr = 0; lyr < L_; ++lyr) {
    ln_fwd<2><<<dim3(M_TOK), dim3(256), 0, stream>>>(
        xbuf, ln1_w + (size_t)lyr * C_, ln1_b + (size_t)lyr * C_, hbuf);
    // qkv -> per-head panels (Q scaled)
    gemm_reg<4><<<dim3((3 * C_ / 128) * GMB_), dim3(256), 0, stream>>>(
        hbuf, wq + (size_t)lyr * 3 * C_ * C_, qkv_b + (size_t)lyr * 3 * C_,
        nullptr, nullptr, 3 * C_, C_, 0, qp, kp, vtp);
    attn_fwd<<<dim3(64, 17), dim3(256), 0, stream>>>(qp, kp, vtp, hbuf);
    // proj: resid += (bias fused)
    gemm_reg<2><<<dim3((C_ / 128) * GMB_), dim3(256), 0, stream>>>(
        hbuf, wp + (size_t)lyr * C_ * C_, proj_b + (size_t)lyr * C_,
        nullptr, xbuf, C_, C_, 0, nullptr, nullptr, nullptr);
    ln_fwd<2><<<dim3(M_TOK), dim3(256), 0, stream>>>(
        xbuf, ln2_w + (size_t)lyr * C_, ln2_b + (size_t)lyr * C_, hbuf);
    // fc1: fast GELU -> packed A for fc2
    gemm_reg<1><<<dim3((HID_ / 128) * GMB_), dim3(256), 0, stream>>>(
        hbuf, w1 + (size_t)lyr * HID_ * C_, fc1_b + (size_t)lyr * HID_,
        big, nullptr, HID_, C_, HID_ >> 5, nullptr, nullptr, nullptr);
    // fc2: K=4096 single pass, resid += (bias fused)
    gemm_reg<2><<<dim3((C_ / 128) * GMB_), dim3(256), 0, stream>>>(
        big, w2 + (size_t)lyr * C_ * HID_, fc2_b + (size_t)lyr * C_,
        nullptr, xbuf, C_, HID_, 0, nullptr, nullptr, nullptr);
  }
  ln_fwd<1><<<dim3(M_TOK), dim3(256), 0, stream>>>(xbuf, norm_w, norm_b, d_out);
}